// Round 5
// baseline (472.340 us; speedup 1.0000x reference)
//
#include <hip/hip_runtime.h>
#include <hip/hip_fp16.h>
#include <math.h>

#define NATOMS 65536

typedef _Float16 f16_t;
typedef __attribute__((ext_vector_type(8))) _Float16 half8;
typedef __attribute__((ext_vector_type(4))) float f32x4;

__constant__ int c_offs[12] = {0,1536,9728,26112,50688,62976,64000,64512,65024,65280,65408,65536};

struct Adj { const int* p[10]; };

__device__ __forceinline__ int seg_of(int row) {
    int s = 0;
#pragma unroll
    for (int i = 1; i <= 10; ++i) s += (row >= c_offs[i]) ? 1 : 0;
    return s;
}

// ---------------- weight packing into MFMA B-fragment layout ----------------
// blob index: (((seg*NNT + ni)*NKB + kb)*512) + lane*8 + j
// blob[lane][j] = W[kb*32 + (lane>>4)*8 + j][ni*16 + (lane&15)]

// gc1: K=192 (75 self | 21 pad | 75 neigh @96 | pad), N=256, 11 segs, NKB=6
__global__ void pack_w1(const float* __restrict__ w0, const float* __restrict__ wself,
                        const float* __restrict__ wneigh, f16_t* __restrict__ Wp) {
    int idx = blockIdx.x * 256 + threadIdx.x;      // 11*16*6*512 = 540672 exact
    int j = idx & 7, lane = (idx >> 3) & 63;
    int kb = (idx >> 9) % 6;
    int rest = idx / (512 * 6);
    int ni = rest & 15, s = rest >> 4;
    int k = kb * 32 + (lane >> 4) * 8 + j;
    int n = ni * 16 + (lane & 15);
    float v = 0.f;
    if (k < 75) v = (s == 0) ? w0[k*256 + n] : wself[((s-1)*75 + k)*256 + n];
    else if (k >= 96 && k < 171 && s > 0) v = wneigh[((s-1)*75 + (k-96))*256 + n];
    Wp[idx] = (f16_t)v;
}

// gc2: K=512 (256 self | 256 neigh), N=256, 11 segs, NKB=16
__global__ void pack_w2(const float* __restrict__ w0, const float* __restrict__ wself,
                        const float* __restrict__ wneigh, f16_t* __restrict__ Wp) {
    int idx = blockIdx.x * 256 + threadIdx.x;      // 11*16*16*512 = 1441792 exact
    int j = idx & 7, lane = (idx >> 3) & 63;
    int kb = (idx >> 9) & 15;
    int rest = idx >> 13;
    int ni = rest & 15, s = rest >> 4;
    int k = kb * 32 + (lane >> 4) * 8 + j;
    int n = ni * 16 + (lane & 15);
    float v = 0.f;
    if (k < 256) v = (s == 0) ? w0[k*256 + n] : wself[((s-1)*256 + k)*256 + n];
    else if (s > 0) v = wneigh[((s-1)*256 + (k-256))*256 + n];
    Wp[idx] = (f16_t)v;
}

// dense: K=256, N=512, 1 seg, NKB=8
__global__ void pack_wd(const float* __restrict__ w, f16_t* __restrict__ Wp) {
    int idx = blockIdx.x * 256 + threadIdx.x;      // 32*8*512 = 131072 exact
    int j = idx & 7, lane = (idx >> 3) & 63;
    int kb = (idx >> 9) & 7;
    int ni = (idx >> 12) & 31;
    int k = kb * 32 + (lane >> 4) * 8 + j;
    int n = ni * 16 + (lane & 15);
    Wp[idx] = (f16_t)w[(size_t)k*512 + n];
}

// ---------------- xq = f16(atom_features) padded 75 -> 96 cols ----------------
__global__ void cvt_pad(const float* __restrict__ xf, f16_t* __restrict__ xq) {
    int idx = blockIdx.x * 256 + threadIdx.x;   // 65536*96 exact
    int r = idx / 96;
    int c = idx - r * 96;
    xq[idx] = (c < 75) ? (f16_t)xf[(size_t)r*75 + c] : (f16_t)0.f;
}

// ---------------- NBX[r] = sum_neigh xq, 96 cols, f16 gather + fp32 accum ----------------
__global__ __launch_bounds__(256) void nbsum_x(const f16_t* __restrict__ xq, f16_t* __restrict__ NBX, Adj adj) {
    int idx = blockIdx.x * 256 + threadIdx.x;   // 65536*12 exact
    int r = idx / 12;
    int cc = idx - r * 12;
    int c = cc << 3;
    int s = seg_of(r);
    float sm[8];
#pragma unroll
    for (int e = 0; e < 8; ++e) sm[e] = 0.f;
    if (s > 0) {
        int loc = r - c_offs[s];
        const int* ap = adj.p[s-1] + (size_t)loc * s;
        for (int j = 0; j < s; ++j) {
            const f16_t* ur = xq + (size_t)ap[j]*96 + c;
#pragma unroll
            for (int e = 0; e < 8; ++e) sm[e] += (float)ur[e];
        }
    }
    f16_t o[8];
#pragma unroll
    for (int e = 0; e < 8; ++e) o[e] = (f16_t)sm[e];
    *(uint4*)(NBX + (size_t)r*96 + c) = *(uint4*)o;
}

// ---------------- graph pool: elementwise max over self+neighbors (f16) ----------------
__global__ __launch_bounds__(256) void pool_k(const f16_t* __restrict__ H, f16_t* __restrict__ P, Adj adj) {
    int idx = blockIdx.x * 256 + threadIdx.x;   // 65536*32 exact
    int r = idx >> 5;
    int c = (idx & 31) << 3;
    int s = seg_of(r);
    const f16_t* hr = H + (size_t)r*256 + c;
    float mx[8];
#pragma unroll
    for (int e = 0; e < 8; ++e) mx[e] = (float)hr[e];
    if (s > 0) {
        int loc = r - c_offs[s];
        const int* ap = adj.p[s-1] + (size_t)loc * s;
        for (int j = 0; j < s; ++j) {
            const f16_t* ur = H + (size_t)ap[j]*256 + c;
#pragma unroll
            for (int e = 0; e < 8; ++e) mx[e] = fmaxf(mx[e], (float)ur[e]);
        }
    }
    f16_t o[8];
#pragma unroll
    for (int e = 0; e < 8; ++e) o[e] = (f16_t)mx[e];
    *(uint4*)(P + (size_t)r*256 + c) = *(uint4*)o;
}

// ---------------- neighbor-sum of pooled features (fp32 accum -> f16), 256 cols ----------------
__global__ __launch_bounds__(256) void nbsum_k(const f16_t* __restrict__ P, f16_t* __restrict__ NB, Adj adj) {
    int idx = blockIdx.x * 256 + threadIdx.x;   // 65536*32 exact
    int r = idx >> 5;
    int c = (idx & 31) << 3;
    int s = seg_of(r);
    float sm[8];
#pragma unroll
    for (int e = 0; e < 8; ++e) sm[e] = 0.f;
    if (s > 0) {
        int loc = r - c_offs[s];
        const int* ap = adj.p[s-1] + (size_t)loc * s;
        for (int j = 0; j < s; ++j) {
            const f16_t* ur = P + (size_t)ap[j]*256 + c;
#pragma unroll
            for (int e = 0; e < 8; ++e) sm[e] += (float)ur[e];
        }
    }
    f16_t o[8];
#pragma unroll
    for (int e = 0; e < 8; ++e) o[e] = (f16_t)sm[e];
    *(uint4*)(NB + (size_t)r*256 + c) = *(uint4*)o;
}

// ---------------- f16 MFMA GEMM, fused bias+relu+bn, LDS-staged coalesced stores ----------------
// C = bn(relu(A @ W[seg] + bias[seg])); A cols [0,KSPLIT) from A0, rest from A1.
// 64x128 tile per block; 4 waves side-by-side in N; wave = 64x32 = 4x2 frags.
// Register double-buffered K-loop (prefetch kb+1 while MFMA kb).
// XCD swizzle: all NY n-tiles of an A row-tile land on one XCD.
template<int K, int KSPLIT, int LDA, int N, int NY, bool SEG>
__global__ __launch_bounds__(256)
void gemm_mfma(const f16_t* __restrict__ A0, const f16_t* __restrict__ A1,
               const f16_t* __restrict__ Wp,
               const float* __restrict__ bias,
               const float* __restrict__ bng, const float* __restrict__ bnb,
               const float* __restrict__ bnm, const float* __restrict__ bnv,
               f16_t* __restrict__ C)
{
    constexpr int NKB = K / 32;
    constexpr int NNT = N / 16;
    __shared__ f16_t lds[64 * 136];   // 17,408 B epilogue staging
    const int t = threadIdx.x;
    const int lane = t & 63, wave = t >> 6;
    const int quad = lane >> 4, l16 = lane & 15;
    // XCD-aware remap (8 XCDs, round-robin dispatch heuristic)
    const int id = blockIdx.x;
    const int xcd = id & 7;
    const int j = id >> 3;
    const int xi = j / NY;
    const int y  = j - xi * NY;
    const int r0 = (xi * 8 + xcd) * 64;
    const int n0 = y * 128;
    const int seg = SEG ? seg_of(r0) : 0;

    f32x4 acc[4][2];
#pragma unroll
    for (int mi = 0; mi < 4; ++mi)
#pragma unroll
        for (int ni = 0; ni < 2; ++ni) acc[mi][ni] = (f32x4){0.f,0.f,0.f,0.f};

    size_t rowoff[4];
#pragma unroll
    for (int mi = 0; mi < 4; ++mi)
        rowoff[mi] = (size_t)(r0 + mi*16 + l16) * LDA + quad*8;
    size_t boff[2];
#pragma unroll
    for (int ni = 0; ni < 2; ++ni) {
        int nt = (n0 >> 4) + wave*2 + ni;
        boff[ni] = (size_t)(seg * NNT + nt) * NKB * 512 + lane*8;
    }

    half8 ca[4], cb[2], na[4], nb[2];
    {
        const f16_t* Abase = (0 < KSPLIT) ? A0 : A1;
#pragma unroll
        for (int mi = 0; mi < 4; ++mi) ca[mi] = *(const half8*)(Abase + rowoff[mi]);
#pragma unroll
        for (int ni = 0; ni < 2; ++ni) cb[ni] = *(const half8*)(Wp + boff[ni]);
    }
#pragma unroll
    for (int kb = 0; kb < NKB; ++kb) {
        if (kb + 1 < NKB) {
            const int kg = (kb + 1) * 32;
            const f16_t* Abase = (kg < KSPLIT) ? (A0 + kg) : (A1 + (kg - KSPLIT));
#pragma unroll
            for (int mi = 0; mi < 4; ++mi) na[mi] = *(const half8*)(Abase + rowoff[mi]);
#pragma unroll
            for (int ni = 0; ni < 2; ++ni) nb[ni] = *(const half8*)(Wp + boff[ni] + (size_t)(kb+1)*512);
        }
#pragma unroll
        for (int mi = 0; mi < 4; ++mi)
#pragma unroll
            for (int ni = 0; ni < 2; ++ni)
                acc[mi][ni] = __builtin_amdgcn_mfma_f32_16x16x32_f16(ca[mi], cb[ni], acc[mi][ni], 0, 0, 0);
#pragma unroll
        for (int mi = 0; mi < 4; ++mi) ca[mi] = na[mi];
#pragma unroll
        for (int ni = 0; ni < 2; ++ni) cb[ni] = nb[ni];
    }

    // epilogue: C/D layout col = lane&15, row = quad*4 + reg -> LDS tile
#pragma unroll
    for (int ni = 0; ni < 2; ++ni) {
        const int lcol = wave*32 + ni*16 + l16;
        const int col = n0 + lcol;
        const float scale = bng[col] * rsqrtf(bnv[col] + 1e-3f);
        const float shift = bnb[col] - bnm[col] * scale;
        const float bv = bias[(SEG ? seg*N : 0) + col];
#pragma unroll
        for (int mi = 0; mi < 4; ++mi) {
            const int lrowb = mi*16 + quad*4;
#pragma unroll
            for (int r = 0; r < 4; ++r) {
                float v = acc[mi][ni][r] + bv;
                v = fmaxf(v, 0.f);
                v = fmaf(v, scale, shift);
                lds[(lrowb + r)*136 + lcol] = (f16_t)v;
            }
        }
    }
    __syncthreads();
    // coalesced store: 16 lanes cover one row's 256 B; 4 iters for 64 rows
#pragma unroll
    for (int it = 0; it < 4; ++it) {
        int row = it*16 + (t >> 4);
        int ch  = t & 15;
        uint4 v = *(const uint4*)&lds[row*136 + ch*8];
        *(uint4*)(C + (size_t)(r0 + row)*N + n0 + ch*8) = v;
    }
}

// ---------------- segment scatter (each segment has exactly 32 atoms) ----------------
__global__ void scatter_k(const int* __restrict__ mem, int* __restrict__ counts, int* __restrict__ slots) {
    int i = blockIdx.x * 256 + threadIdx.x;   // 65536 exact
    int s = mem[i];
    int p = atomicAdd(&counts[s], 1);
    if (p < 32) slots[s*32 + p] = i;
}

// ---------------- segment sum/max over H3[65536x512] f16 -> fp = tanh([ssum|smax]) ----------------
__global__ __launch_bounds__(256)
void reduce_k(const f16_t* __restrict__ H3, const int* __restrict__ counts,
              const int* __restrict__ slots, float* __restrict__ fp) {
    int s = blockIdx.x, t = threadIdx.x;
    int cnt = counts[s]; if (cnt > 32) cnt = 32;
    float s0 = 0.f, s1 = 0.f, m0 = -INFINITY, m1 = -INFINITY;
    for (int i = 0; i < cnt; ++i) {
        int a = slots[s*32 + i];
        const f16_t* hr = H3 + (size_t)a*512;
        float v0 = (float)hr[t], v1 = (float)hr[t+256];
        s0 += v0; s1 += v1;
        m0 = fmaxf(m0, v0); m1 = fmaxf(m1, v1);
    }
    float* fr = fp + (size_t)s*1024;
    fr[t]       = tanhf(s0);
    fr[t+256]   = tanhf(s1);
    fr[512+t]   = tanhf(m0);
    fr[768+t]   = tanhf(m1);
}

// ---------------- logits = fp @ out_w + out_b; probs = softmax(pairs) ----------------
__global__ __launch_bounds__(256)
void final_k(const float* __restrict__ fp, const float* __restrict__ out_w,
             const float* __restrict__ out_b, float* __restrict__ probs, float* __restrict__ logits) {
    __shared__ float row[1024];
    __shared__ float lg[24];
    int s = blockIdx.x, t = threadIdx.x;
    const float* fr = fp + (size_t)s*1024;
    *(float4*)&row[t*4] = *(const float4*)&fr[t*4];
    __syncthreads();
    if (t < 192) {
        int o = t >> 3;
        int k0 = (t & 7) * 128;
        float acc = 0.f;
        for (int k = 0; k < 128; ++k)
            acc = fmaf(row[k0+k], out_w[(size_t)(k0+k)*24 + o], acc);
        acc += __shfl_xor(acc, 1);
        acc += __shfl_xor(acc, 2);
        acc += __shfl_xor(acc, 4);
        if ((t & 7) == 0) lg[o] = acc + out_b[o];
    }
    __syncthreads();
    if (t < 12) {
        float l0 = lg[2*t], l1 = lg[2*t+1];
        float m = fmaxf(l0, l1);
        float e0 = expf(l0-m), e1 = expf(l1-m);
        float inv = 1.f / (e0 + e1);
        int base = s*24 + 2*t;
        probs[base]   = e0*inv;  probs[base+1]  = e1*inv;
        logits[base]  = l0;      logits[base+1] = l1;
    }
}

extern "C" void kernel_launch(void* const* d_in, const int* in_sizes, int n_in,
                              void* d_out, int out_size, void* d_ws, size_t ws_size,
                              hipStream_t stream) {
    const float* atom       = (const float*)d_in[0];
    const int*   membership = (const int*)  d_in[2];
    Adj adj;
    for (int d = 0; d < 10; ++d) adj.p[d] = (const int*)d_in[4+d];
    const float* gc1_w0     = (const float*)d_in[14];
    const float* gc1_wself  = (const float*)d_in[15];
    const float* gc1_wneigh = (const float*)d_in[16];
    const float* gc1_b      = (const float*)d_in[17];
    const float* gc2_w0     = (const float*)d_in[18];
    const float* gc2_wself  = (const float*)d_in[19];
    const float* gc2_wneigh = (const float*)d_in[20];
    const float* gc2_b      = (const float*)d_in[21];
    const float* bn1g = (const float*)d_in[22]; const float* bn1b = (const float*)d_in[23];
    const float* bn1m = (const float*)d_in[24]; const float* bn1v = (const float*)d_in[25];
    const float* bn2g = (const float*)d_in[26]; const float* bn2b = (const float*)d_in[27];
    const float* bn2m = (const float*)d_in[28]; const float* bn2v = (const float*)d_in[29];
    const float* bn3g = (const float*)d_in[30]; const float* bn3b = (const float*)d_in[31];
    const float* bn3m = (const float*)d_in[32]; const float* bn3v = (const float*)d_in[33];
    const float* dense_w = (const float*)d_in[34];
    const float* dense_b = (const float*)d_in[35];
    const float* out_w   = (const float*)d_in[36];
    const float* out_b   = (const float*)d_in[37];

    // workspace layout in f16 elements (2 B each); aliasing:
    //   H2 = H1; P2 = NB2 slot; H3 = H1+P1 span (all dead by their reuse points)
    f16_t* wsb = (f16_t*)d_ws;
    f16_t* xq   = wsb;                       //  6,291,456
    f16_t* NBX  = wsb + 6291456;             //  6,291,456
    f16_t* H1b  = wsb + 12582912;            // 16,777,216
    f16_t* P1b  = wsb + 29360128;            // 16,777,216
    f16_t* NB2b = wsb + 46137344;            // 16,777,216
    f16_t* H2b  = H1b;
    f16_t* P2b  = NB2b;
    f16_t* H3b  = H1b;                       // 33,554,432 spans H1+P1
    f16_t* W1p  = wsb + 62914560;            //    540,672
    f16_t* W2p  = wsb + 63455232;            //  1,441,792
    f16_t* Wdp  = wsb + 64897024;            //    131,072
    int*  counts = (int*)(wsb + 65028096);   // 2048 ints
    int*  slots  = counts + 2048;            // 65536 ints

    float* outp   = (float*)d_out;
    float* probs  = outp;            // 2048*24
    float* logits = outp + 49152;    // 2048*24
    float* fp     = outp + 98304;    // 2048*1024

    // weight packing
    pack_w1<<<2112, 256, 0, stream>>>(gc1_w0, gc1_wself, gc1_wneigh, W1p);
    pack_w2<<<5632, 256, 0, stream>>>(gc2_w0, gc2_wself, gc2_wneigh, W2p);
    pack_wd<<<512,  256, 0, stream>>>(dense_w, Wdp);

    // gc1: xq (self, k<96) + NBX (neigh, k>=96)
    cvt_pad<<<(NATOMS*96)/256, 256, 0, stream>>>(atom, xq);
    nbsum_x<<<(NATOMS*12)/256, 256, 0, stream>>>(xq, NBX, adj);
    gemm_mfma<192,96,96,256,2,true><<<2048, 256, 0, stream>>>(
        xq, NBX, W1p, gc1_b, bn1g, bn1b, bn1m, bn1v, H1b);
    pool_k<<<(NATOMS*32)/256, 256, 0, stream>>>(H1b, P1b, adj);

    // gc2
    nbsum_k<<<(NATOMS*32)/256, 256, 0, stream>>>(P1b, NB2b, adj);
    gemm_mfma<512,256,256,256,2,true><<<2048, 256, 0, stream>>>(
        P1b, NB2b, W2p, gc2_b, bn2g, bn2b, bn2m, bn2v, H2b);
    pool_k<<<(NATOMS*32)/256, 256, 0, stream>>>(H2b, P2b, adj);

    // dense
    gemm_mfma<256,256,256,512,4,false><<<4096, 256, 0, stream>>>(
        P2b, P2b, Wdp, dense_b, bn3g, bn3b, bn3m, bn3v, H3b);

    // segment reduce + tanh -> fp
    hipMemsetAsync((void*)counts, 0, 2048*sizeof(int), stream);
    scatter_k<<<NATOMS/256, 256, 0, stream>>>(membership, counts, slots);
    reduce_k<<<2048, 256, 0, stream>>>(H3b, counts, slots, fp);

    // readout
    final_k<<<2048, 256, 0, stream>>>(fp, out_w, out_b, probs, logits);
}

// Round 6
// 437.905 us; speedup vs baseline: 1.0786x; 1.0786x over previous
//
#include <hip/hip_runtime.h>
#include <hip/hip_fp16.h>
#include <math.h>

#define NATOMS 65536

typedef _Float16 f16_t;
typedef __attribute__((ext_vector_type(8))) _Float16 half8;
typedef __attribute__((ext_vector_type(4))) float f32x4;

__constant__ int c_offs[12] = {0,1536,9728,26112,50688,62976,64000,64512,65024,65280,65408,65536};

struct Adj { const int* p[10]; };

__device__ __forceinline__ int seg_of(int row) {
    int s = 0;
#pragma unroll
    for (int i = 1; i <= 10; ++i) s += (row >= c_offs[i]) ? 1 : 0;
    return s;
}

// ---------------- weight packing into MFMA B-fragment layout ----------------
// blob index: (((seg*NNT + ni)*NKB + kb)*512) + lane*8 + j
// blob[lane][j] = W[kb*32 + (lane>>4)*8 + j][ni*16 + (lane&15)]

// gc1: K=192 (75 self | 21 pad | 75 neigh @96 | pad), N=256, 11 segs, NKB=6
__global__ void pack_w1(const float* __restrict__ w0, const float* __restrict__ wself,
                        const float* __restrict__ wneigh, f16_t* __restrict__ Wp) {
    int idx = blockIdx.x * 256 + threadIdx.x;      // 11*16*6*512 = 540672 exact
    int j = idx & 7, lane = (idx >> 3) & 63;
    int kb = (idx >> 9) % 6;
    int rest = idx / (512 * 6);
    int ni = rest & 15, s = rest >> 4;
    int k = kb * 32 + (lane >> 4) * 8 + j;
    int n = ni * 16 + (lane & 15);
    float v = 0.f;
    if (k < 75) v = (s == 0) ? w0[k*256 + n] : wself[((s-1)*75 + k)*256 + n];
    else if (k >= 96 && k < 171 && s > 0) v = wneigh[((s-1)*75 + (k-96))*256 + n];
    Wp[idx] = (f16_t)v;
}

// gc2: K=512 (256 self | 256 neigh), N=256, 11 segs, NKB=16
__global__ void pack_w2(const float* __restrict__ w0, const float* __restrict__ wself,
                        const float* __restrict__ wneigh, f16_t* __restrict__ Wp) {
    int idx = blockIdx.x * 256 + threadIdx.x;      // 11*16*16*512 = 1441792 exact
    int j = idx & 7, lane = (idx >> 3) & 63;
    int kb = (idx >> 9) & 15;
    int rest = idx >> 13;
    int ni = rest & 15, s = rest >> 4;
    int k = kb * 32 + (lane >> 4) * 8 + j;
    int n = ni * 16 + (lane & 15);
    float v = 0.f;
    if (k < 256) v = (s == 0) ? w0[k*256 + n] : wself[((s-1)*256 + k)*256 + n];
    else if (s > 0) v = wneigh[((s-1)*256 + (k-256))*256 + n];
    Wp[idx] = (f16_t)v;
}

// dense: K=256, N=512, 1 seg, NKB=8
__global__ void pack_wd(const float* __restrict__ w, f16_t* __restrict__ Wp) {
    int idx = blockIdx.x * 256 + threadIdx.x;      // 32*8*512 = 131072 exact
    int j = idx & 7, lane = (idx >> 3) & 63;
    int kb = (idx >> 9) & 7;
    int ni = (idx >> 12) & 31;
    int k = kb * 32 + (lane >> 4) * 8 + j;
    int n = ni * 16 + (lane & 15);
    Wp[idx] = (f16_t)w[(size_t)k*512 + n];
}

// ---------------- xq = f16(atom_features) padded 75 -> 96 cols ----------------
__global__ void cvt_pad(const float* __restrict__ xf, f16_t* __restrict__ xq) {
    int idx = blockIdx.x * 256 + threadIdx.x;   // 65536*96 exact
    int r = idx / 96;
    int c = idx - r * 96;
    xq[idx] = (c < 75) ? (f16_t)xf[(size_t)r*75 + c] : (f16_t)0.f;
}

// ---------------- NBX[r] = sum_neigh xq, 96 cols, f16 gather + fp32 accum ----------------
__global__ __launch_bounds__(256) void nbsum_x(const f16_t* __restrict__ xq, f16_t* __restrict__ NBX, Adj adj) {
    int idx = blockIdx.x * 256 + threadIdx.x;   // 65536*12 exact
    int r = idx / 12;
    int cc = idx - r * 12;
    int c = cc << 3;
    int s = seg_of(r);
    float sm[8];
#pragma unroll
    for (int e = 0; e < 8; ++e) sm[e] = 0.f;
    if (s > 0) {
        int loc = r - c_offs[s];
        const int* ap = adj.p[s-1] + (size_t)loc * s;
        for (int j = 0; j < s; ++j) {
            const f16_t* ur = xq + (size_t)ap[j]*96 + c;
#pragma unroll
            for (int e = 0; e < 8; ++e) sm[e] += (float)ur[e];
        }
    }
    f16_t o[8];
#pragma unroll
    for (int e = 0; e < 8; ++e) o[e] = (f16_t)sm[e];
    *(uint4*)(NBX + (size_t)r*96 + c) = *(uint4*)o;
}

// ---------------- graph pool: elementwise max over self+neighbors (f16) ----------------
__global__ __launch_bounds__(256) void pool_k(const f16_t* __restrict__ H, f16_t* __restrict__ P, Adj adj) {
    int idx = blockIdx.x * 256 + threadIdx.x;   // 65536*32 exact
    int r = idx >> 5;
    int c = (idx & 31) << 3;
    int s = seg_of(r);
    const f16_t* hr = H + (size_t)r*256 + c;
    float mx[8];
#pragma unroll
    for (int e = 0; e < 8; ++e) mx[e] = (float)hr[e];
    if (s > 0) {
        int loc = r - c_offs[s];
        const int* ap = adj.p[s-1] + (size_t)loc * s;
        for (int j = 0; j < s; ++j) {
            const f16_t* ur = H + (size_t)ap[j]*256 + c;
#pragma unroll
            for (int e = 0; e < 8; ++e) mx[e] = fmaxf(mx[e], (float)ur[e]);
        }
    }
    f16_t o[8];
#pragma unroll
    for (int e = 0; e < 8; ++e) o[e] = (f16_t)mx[e];
    *(uint4*)(P + (size_t)r*256 + c) = *(uint4*)o;
}

// ---------------- neighbor-sum of pooled features (fp32 accum -> f16), 256 cols ----------------
__global__ __launch_bounds__(256) void nbsum_k(const f16_t* __restrict__ P, f16_t* __restrict__ NB, Adj adj) {
    int idx = blockIdx.x * 256 + threadIdx.x;   // 65536*32 exact
    int r = idx >> 5;
    int c = (idx & 31) << 3;
    int s = seg_of(r);
    float sm[8];
#pragma unroll
    for (int e = 0; e < 8; ++e) sm[e] = 0.f;
    if (s > 0) {
        int loc = r - c_offs[s];
        const int* ap = adj.p[s-1] + (size_t)loc * s;
        for (int j = 0; j < s; ++j) {
            const f16_t* ur = P + (size_t)ap[j]*256 + c;
#pragma unroll
            for (int e = 0; e < 8; ++e) sm[e] += (float)ur[e];
        }
    }
    f16_t o[8];
#pragma unroll
    for (int e = 0; e < 8; ++e) o[e] = (f16_t)sm[e];
    *(uint4*)(NB + (size_t)r*256 + c) = *(uint4*)o;
}

// ---------------- f16 MFMA GEMM, fused bias+relu+bn, LDS-staged coalesced stores ----------------
// C = bn(relu(A @ W[seg] + bias[seg])); A cols [0,KSPLIT) from A0, rest from A1.
// 128x128 tile per block; 4 waves 2x2; wave 64x64 = 4x4 frags.
// Modulo-2 software pipeline: two live buffer sets (a0/b0, a1/b1) alternate so
// each wave always has the next K-step's 8 loads in flight while MFMAing.
// XCD swizzle: all NY n-tiles of an A row-tile land on one XCD.
template<int K, int KSPLIT, int LDA, int N, int NY, bool SEG>
__global__ __launch_bounds__(256)
void gemm_mfma(const f16_t* __restrict__ A0, const f16_t* __restrict__ A1,
               const f16_t* __restrict__ Wp,
               const float* __restrict__ bias,
               const float* __restrict__ bng, const float* __restrict__ bnb,
               const float* __restrict__ bnm, const float* __restrict__ bnv,
               f16_t* __restrict__ C)
{
    constexpr int NKB = K / 32;   // even for all instantiations (6, 16, 8)
    constexpr int NNT = N / 16;
    __shared__ f16_t lds[128 * 136];
    const int t = threadIdx.x;
    const int lane = t & 63, wave = t >> 6;
    const int wm = wave >> 1, wn = wave & 1;
    const int quad = lane >> 4, l16 = lane & 15;
    // XCD-aware remap (8 XCDs, round-robin dispatch heuristic)
    const int id = blockIdx.x;
    const int xcd = id & 7;
    const int jj = id >> 3;
    const int xi = jj / NY;
    const int y  = jj - xi * NY;
    const int r0 = (xi * 8 + xcd) * 128;
    const int n0 = y * 128;
    const int seg = SEG ? seg_of(r0) : 0;

    f32x4 acc[4][4];
#pragma unroll
    for (int mi = 0; mi < 4; ++mi)
#pragma unroll
        for (int ni = 0; ni < 4; ++ni) acc[mi][ni] = (f32x4){0.f,0.f,0.f,0.f};

    size_t rowoff[4];
#pragma unroll
    for (int mi = 0; mi < 4; ++mi)
        rowoff[mi] = (size_t)(r0 + wm*64 + mi*16 + l16) * LDA + quad*8;
    size_t boff[4];
#pragma unroll
    for (int ni = 0; ni < 4; ++ni) {
        int nt = (n0 >> 4) + wn*4 + ni;
        boff[ni] = (size_t)(seg * NNT + nt) * NKB * 512 + lane*8;
    }

    auto loadA = [&](half8* a, int kb) {
        const int kg = kb * 32;
        const f16_t* Ab = (kg < KSPLIT) ? (A0 + kg) : (A1 + (kg - KSPLIT));
#pragma unroll
        for (int mi = 0; mi < 4; ++mi) a[mi] = *(const half8*)(Ab + rowoff[mi]);
    };
    auto loadB = [&](half8* b, int kb) {
#pragma unroll
        for (int ni = 0; ni < 4; ++ni) b[ni] = *(const half8*)(Wp + boff[ni] + (size_t)kb*512);
    };
    auto domfma = [&](half8* a, half8* b) {
#pragma unroll
        for (int mi = 0; mi < 4; ++mi)
#pragma unroll
            for (int ni = 0; ni < 4; ++ni)
                acc[mi][ni] = __builtin_amdgcn_mfma_f32_16x16x32_f16(a[mi], b[ni], acc[mi][ni], 0, 0, 0);
    };

    half8 a0[4], b0[4], a1[4], b1[4];
    loadA(a0, 0); loadB(b0, 0);
#pragma unroll
    for (int kb = 0; kb < NKB; kb += 2) {
        loadA(a1, kb + 1); loadB(b1, kb + 1);     // in flight during compute(a0)
        domfma(a0, b0);
        if (kb + 2 < NKB) { loadA(a0, kb + 2); loadB(b0, kb + 2); }  // in flight during compute(a1)
        domfma(a1, b1);
    }

    // epilogue: C/D layout col = lane&15, row = quad*4 + reg -> LDS tile
#pragma unroll
    for (int ni = 0; ni < 4; ++ni) {
        const int lcol = (wn*4 + ni)*16 + l16;
        const int col = n0 + lcol;
        const float scale = bng[col] * rsqrtf(bnv[col] + 1e-3f);
        const float shift = bnb[col] - bnm[col] * scale;
        const float bv = bias[(SEG ? seg*N : 0) + col];
#pragma unroll
        for (int mi = 0; mi < 4; ++mi) {
            const int lrowb = wm*64 + mi*16 + quad*4;
#pragma unroll
            for (int r = 0; r < 4; ++r) {
                float v = acc[mi][ni][r] + bv;
                v = fmaxf(v, 0.f);
                v = fmaf(v, scale, shift);
                lds[(lrowb + r)*136 + lcol] = (f16_t)v;
            }
        }
    }
    __syncthreads();
    // coalesced store: 16 lanes cover one row's 256 B; 8 iters for 128 rows
#pragma unroll
    for (int it = 0; it < 8; ++it) {
        int row = it*16 + (t >> 4);
        int ch  = t & 15;
        uint4 v = *(const uint4*)&lds[row*136 + ch*8];
        *(uint4*)(C + (size_t)(r0 + row)*N + n0 + ch*8) = v;
    }
}

// ---------------- segment scatter (each segment has exactly 32 atoms) ----------------
__global__ void scatter_k(const int* __restrict__ mem, int* __restrict__ counts, int* __restrict__ slots) {
    int i = blockIdx.x * 256 + threadIdx.x;   // 65536 exact
    int s = mem[i];
    int p = atomicAdd(&counts[s], 1);
    if (p < 32) slots[s*32 + p] = i;
}

// ---------------- segment sum/max over H3[65536x512] f16 -> fp = tanh([ssum|smax]) ----------------
__global__ __launch_bounds__(256)
void reduce_k(const f16_t* __restrict__ H3, const int* __restrict__ counts,
              const int* __restrict__ slots, float* __restrict__ fp) {
    int s = blockIdx.x, t = threadIdx.x;
    int cnt = counts[s]; if (cnt > 32) cnt = 32;
    float s0 = 0.f, s1 = 0.f, m0 = -INFINITY, m1 = -INFINITY;
    for (int i = 0; i < cnt; ++i) {
        int a = slots[s*32 + i];
        const f16_t* hr = H3 + (size_t)a*512;
        float v0 = (float)hr[t], v1 = (float)hr[t+256];
        s0 += v0; s1 += v1;
        m0 = fmaxf(m0, v0); m1 = fmaxf(m1, v1);
    }
    float* fr = fp + (size_t)s*1024;
    fr[t]       = tanhf(s0);
    fr[t+256]   = tanhf(s1);
    fr[512+t]   = tanhf(m0);
    fr[768+t]   = tanhf(m1);
}

// ---------------- logits = fp @ out_w + out_b; probs = softmax(pairs) ----------------
__global__ __launch_bounds__(256)
void final_k(const float* __restrict__ fp, const float* __restrict__ out_w,
             const float* __restrict__ out_b, float* __restrict__ probs, float* __restrict__ logits) {
    __shared__ float row[1024];
    __shared__ float lg[24];
    int s = blockIdx.x, t = threadIdx.x;
    const float* fr = fp + (size_t)s*1024;
    *(float4*)&row[t*4] = *(const float4*)&fr[t*4];
    __syncthreads();
    if (t < 192) {
        int o = t >> 3;
        int k0 = (t & 7) * 128;
        float acc = 0.f;
        for (int k = 0; k < 128; ++k)
            acc = fmaf(row[k0+k], out_w[(size_t)(k0+k)*24 + o], acc);
        acc += __shfl_xor(acc, 1);
        acc += __shfl_xor(acc, 2);
        acc += __shfl_xor(acc, 4);
        if ((t & 7) == 0) lg[o] = acc + out_b[o];
    }
    __syncthreads();
    if (t < 12) {
        float l0 = lg[2*t], l1 = lg[2*t+1];
        float m = fmaxf(l0, l1);
        float e0 = expf(l0-m), e1 = expf(l1-m);
        float inv = 1.f / (e0 + e1);
        int base = s*24 + 2*t;
        probs[base]   = e0*inv;  probs[base+1]  = e1*inv;
        logits[base]  = l0;      logits[base+1] = l1;
    }
}

extern "C" void kernel_launch(void* const* d_in, const int* in_sizes, int n_in,
                              void* d_out, int out_size, void* d_ws, size_t ws_size,
                              hipStream_t stream) {
    const float* atom       = (const float*)d_in[0];
    const int*   membership = (const int*)  d_in[2];
    Adj adj;
    for (int d = 0; d < 10; ++d) adj.p[d] = (const int*)d_in[4+d];
    const float* gc1_w0     = (const float*)d_in[14];
    const float* gc1_wself  = (const float*)d_in[15];
    const float* gc1_wneigh = (const float*)d_in[16];
    const float* gc1_b      = (const float*)d_in[17];
    const float* gc2_w0     = (const float*)d_in[18];
    const float* gc2_wself  = (const float*)d_in[19];
    const float* gc2_wneigh = (const float*)d_in[20];
    const float* gc2_b      = (const float*)d_in[21];
    const float* bn1g = (const float*)d_in[22]; const float* bn1b = (const float*)d_in[23];
    const float* bn1m = (const float*)d_in[24]; const float* bn1v = (const float*)d_in[25];
    const float* bn2g = (const float*)d_in[26]; const float* bn2b = (const float*)d_in[27];
    const float* bn2m = (const float*)d_in[28]; const float* bn2v = (const float*)d_in[29];
    const float* bn3g = (const float*)d_in[30]; const float* bn3b = (const float*)d_in[31];
    const float* bn3m = (const float*)d_in[32]; const float* bn3v = (const float*)d_in[33];
    const float* dense_w = (const float*)d_in[34];
    const float* dense_b = (const float*)d_in[35];
    const float* out_w   = (const float*)d_in[36];
    const float* out_b   = (const float*)d_in[37];

    // workspace layout in f16 elements (2 B each); aliasing:
    //   H2 = H1; P2 = NB2 slot; H3 = H1+P1 span (all dead by their reuse points)
    f16_t* wsb = (f16_t*)d_ws;
    f16_t* xq   = wsb;                       //  6,291,456
    f16_t* NBX  = wsb + 6291456;             //  6,291,456
    f16_t* H1b  = wsb + 12582912;            // 16,777,216
    f16_t* P1b  = wsb + 29360128;            // 16,777,216
    f16_t* NB2b = wsb + 46137344;            // 16,777,216
    f16_t* H2b  = H1b;
    f16_t* P2b  = NB2b;
    f16_t* H3b  = H1b;                       // 33,554,432 spans H1+P1
    f16_t* W1p  = wsb + 62914560;            //    540,672
    f16_t* W2p  = wsb + 63455232;            //  1,441,792
    f16_t* Wdp  = wsb + 64897024;            //    131,072
    int*  counts = (int*)(wsb + 65028096);   // 2048 ints
    int*  slots  = counts + 2048;            // 65536 ints

    float* outp   = (float*)d_out;
    float* probs  = outp;            // 2048*24
    float* logits = outp + 49152;    // 2048*24
    float* fp     = outp + 98304;    // 2048*1024

    // weight packing
    pack_w1<<<2112, 256, 0, stream>>>(gc1_w0, gc1_wself, gc1_wneigh, W1p);
    pack_w2<<<5632, 256, 0, stream>>>(gc2_w0, gc2_wself, gc2_wneigh, W2p);
    pack_wd<<<512,  256, 0, stream>>>(dense_w, Wdp);

    // gc1: xq (self, k<96) + NBX (neigh, k>=96)
    cvt_pad<<<(NATOMS*96)/256, 256, 0, stream>>>(atom, xq);
    nbsum_x<<<(NATOMS*12)/256, 256, 0, stream>>>(xq, NBX, adj);
    gemm_mfma<192,96,96,256,2,true><<<1024, 256, 0, stream>>>(
        xq, NBX, W1p, gc1_b, bn1g, bn1b, bn1m, bn1v, H1b);
    pool_k<<<(NATOMS*32)/256, 256, 0, stream>>>(H1b, P1b, adj);

    // gc2
    nbsum_k<<<(NATOMS*32)/256, 256, 0, stream>>>(P1b, NB2b, adj);
    gemm_mfma<512,256,256,256,2,true><<<1024, 256, 0, stream>>>(
        P1b, NB2b, W2p, gc2_b, bn2g, bn2b, bn2m, bn2v, H2b);
    pool_k<<<(NATOMS*32)/256, 256, 0, stream>>>(H2b, P2b, adj);

    // dense
    gemm_mfma<256,256,256,512,4,false><<<2048, 256, 0, stream>>>(
        P2b, P2b, Wdp, dense_b, bn3g, bn3b, bn3m, bn3v, H3b);

    // segment reduce + tanh -> fp
    hipMemsetAsync((void*)counts, 0, 2048*sizeof(int), stream);
    scatter_k<<<NATOMS/256, 256, 0, stream>>>(membership, counts, slots);
    reduce_k<<<2048, 256, 0, stream>>>(H3b, counts, slots, fp);

    // readout
    final_k<<<2048, 256, 0, stream>>>(fp, out_w, out_b, probs, logits);
}

// Round 7
// 390.977 us; speedup vs baseline: 1.2081x; 1.1200x over previous
//
#include <hip/hip_runtime.h>
#include <hip/hip_fp16.h>
#include <math.h>

#define NATOMS 65536

typedef _Float16 f16_t;
typedef __attribute__((ext_vector_type(8))) _Float16 half8;
typedef __attribute__((ext_vector_type(4))) float f32x4;

__constant__ int c_offs[12] = {0,1536,9728,26112,50688,62976,64000,64512,65024,65280,65408,65536};

struct Adj { const int* p[10]; };

__device__ __forceinline__ int seg_of(int row) {
    int s = 0;
#pragma unroll
    for (int i = 1; i <= 10; ++i) s += (row >= c_offs[i]) ? 1 : 0;
    return s;
}

// async global -> LDS, 16 B per lane; LDS dst = wave-uniform base + lane*16
__device__ __forceinline__ void glds16(const f16_t* g, f16_t* l) {
    __builtin_amdgcn_global_load_lds(
        (const __attribute__((address_space(1))) unsigned int*)g,
        (__attribute__((address_space(3))) unsigned int*)l,
        16, 0, 0);
}

// ---------------- weight packing into MFMA B-fragment layout ----------------
// blob index: (((seg*NNT + ni)*NKB + kb)*512) + lane*8 + j
// blob[lane][j] = W[kb*32 + (lane>>4)*8 + j][ni*16 + (lane&15)]

__global__ void pack_w1(const float* __restrict__ w0, const float* __restrict__ wself,
                        const float* __restrict__ wneigh, f16_t* __restrict__ Wp) {
    int idx = blockIdx.x * 256 + threadIdx.x;      // 11*16*6*512 = 540672 exact
    int j = idx & 7, lane = (idx >> 3) & 63;
    int kb = (idx >> 9) % 6;
    int rest = idx / (512 * 6);
    int ni = rest & 15, s = rest >> 4;
    int k = kb * 32 + (lane >> 4) * 8 + j;
    int n = ni * 16 + (lane & 15);
    float v = 0.f;
    if (k < 75) v = (s == 0) ? w0[k*256 + n] : wself[((s-1)*75 + k)*256 + n];
    else if (k >= 96 && k < 171 && s > 0) v = wneigh[((s-1)*75 + (k-96))*256 + n];
    Wp[idx] = (f16_t)v;
}

__global__ void pack_w2(const float* __restrict__ w0, const float* __restrict__ wself,
                        const float* __restrict__ wneigh, f16_t* __restrict__ Wp) {
    int idx = blockIdx.x * 256 + threadIdx.x;      // 11*16*16*512 = 1441792 exact
    int j = idx & 7, lane = (idx >> 3) & 63;
    int kb = (idx >> 9) & 15;
    int rest = idx >> 13;
    int ni = rest & 15, s = rest >> 4;
    int k = kb * 32 + (lane >> 4) * 8 + j;
    int n = ni * 16 + (lane & 15);
    float v = 0.f;
    if (k < 256) v = (s == 0) ? w0[k*256 + n] : wself[((s-1)*256 + k)*256 + n];
    else if (s > 0) v = wneigh[((s-1)*256 + (k-256))*256 + n];
    Wp[idx] = (f16_t)v;
}

__global__ void pack_wd(const float* __restrict__ w, f16_t* __restrict__ Wp) {
    int idx = blockIdx.x * 256 + threadIdx.x;      // 32*8*512 = 131072 exact
    int j = idx & 7, lane = (idx >> 3) & 63;
    int kb = (idx >> 9) & 7;
    int ni = (idx >> 12) & 31;
    int k = kb * 32 + (lane >> 4) * 8 + j;
    int n = ni * 16 + (lane & 15);
    Wp[idx] = (f16_t)w[(size_t)k*512 + n];
}

// ---------------- xq = f16(atom_features) padded 75 -> 96 cols ----------------
__global__ void cvt_pad(const float* __restrict__ xf, f16_t* __restrict__ xq) {
    int idx = blockIdx.x * 256 + threadIdx.x;   // 65536*96 exact
    int r = idx / 96;
    int c = idx - r * 96;
    xq[idx] = (c < 75) ? (f16_t)xf[(size_t)r*75 + c] : (f16_t)0.f;
}

// ---------------- compile-time-degree gather helpers ----------------
template<int D, bool ISMAX, int LD>
__device__ __forceinline__ void gathD(float* v, const f16_t* __restrict__ src,
                                      const int* __restrict__ ap, int c) {
    int rows[D];
#pragma unroll
    for (int j = 0; j < D; ++j) rows[j] = ap[j];
    uint4 raw[D];
#pragma unroll
    for (int j = 0; j < D; ++j) raw[j] = *(const uint4*)(src + (size_t)rows[j]*LD + c);
#pragma unroll
    for (int j = 0; j < D; ++j) {
        const f16_t* u = (const f16_t*)&raw[j];
#pragma unroll
        for (int e = 0; e < 8; ++e) {
            float f = (float)u[e];
            v[e] = ISMAX ? fmaxf(v[e], f) : (v[e] + f);
        }
    }
}

template<bool ISMAX, int LD>
__device__ __forceinline__ void gath_switch(float* v, const f16_t* __restrict__ src,
                                            const int* __restrict__ ap, int s, int c) {
    switch (s) {   // per-block uniform (segment boundaries are multiples of 128)
        case 1:  gathD<1,ISMAX,LD>(v,src,ap,c);  break;
        case 2:  gathD<2,ISMAX,LD>(v,src,ap,c);  break;
        case 3:  gathD<3,ISMAX,LD>(v,src,ap,c);  break;
        case 4:  gathD<4,ISMAX,LD>(v,src,ap,c);  break;
        case 5:  gathD<5,ISMAX,LD>(v,src,ap,c);  break;
        case 6:  gathD<6,ISMAX,LD>(v,src,ap,c);  break;
        case 7:  gathD<7,ISMAX,LD>(v,src,ap,c);  break;
        case 8:  gathD<8,ISMAX,LD>(v,src,ap,c);  break;
        case 9:  gathD<9,ISMAX,LD>(v,src,ap,c);  break;
        case 10: gathD<10,ISMAX,LD>(v,src,ap,c); break;
        default: break;
    }
}

// ---------------- NBX[r] = sum_neigh xq, 96 cols ----------------
__global__ __launch_bounds__(256) void nbsum_x(const f16_t* __restrict__ xq, f16_t* __restrict__ NBX, Adj adj) {
    int idx = blockIdx.x * 256 + threadIdx.x;   // 65536*16 exact, cc>=12 idle
    int r = idx >> 4;
    int cc = idx & 15;
    if (cc >= 12) return;
    int c = cc << 3;
    int s = seg_of(r);
    float v[8];
#pragma unroll
    for (int e = 0; e < 8; ++e) v[e] = 0.f;
    if (s > 0)
        gath_switch<false,96>(v, xq, adj.p[s-1] + (size_t)(r - c_offs[s]) * s, s, c);
    f16_t o[8];
#pragma unroll
    for (int e = 0; e < 8; ++e) o[e] = (f16_t)v[e];
    *(uint4*)(NBX + (size_t)r*96 + c) = *(uint4*)o;
}

// ---------------- graph pool: elementwise max over self+neighbors ----------------
__global__ __launch_bounds__(256) void pool_k(const f16_t* __restrict__ H, f16_t* __restrict__ P, Adj adj) {
    int idx = blockIdx.x * 256 + threadIdx.x;   // 65536*32 exact
    int r = idx >> 5;
    int c = (idx & 31) << 3;
    int s = seg_of(r);
    uint4 self = *(const uint4*)(H + (size_t)r*256 + c);
    const f16_t* hp = (const f16_t*)&self;
    float v[8];
#pragma unroll
    for (int e = 0; e < 8; ++e) v[e] = (float)hp[e];
    if (s > 0)
        gath_switch<true,256>(v, H, adj.p[s-1] + (size_t)(r - c_offs[s]) * s, s, c);
    f16_t o[8];
#pragma unroll
    for (int e = 0; e < 8; ++e) o[e] = (f16_t)v[e];
    *(uint4*)(P + (size_t)r*256 + c) = *(uint4*)o;
}

// ---------------- neighbor-sum of pooled features, 256 cols ----------------
__global__ __launch_bounds__(256) void nbsum_k(const f16_t* __restrict__ P, f16_t* __restrict__ NB, Adj adj) {
    int idx = blockIdx.x * 256 + threadIdx.x;   // 65536*32 exact
    int r = idx >> 5;
    int c = (idx & 31) << 3;
    int s = seg_of(r);
    float v[8];
#pragma unroll
    for (int e = 0; e < 8; ++e) v[e] = 0.f;
    if (s > 0)
        gath_switch<false,256>(v, P, adj.p[s-1] + (size_t)(r - c_offs[s]) * s, s, c);
    f16_t o[8];
#pragma unroll
    for (int e = 0; e < 8; ++e) o[e] = (f16_t)v[e];
    *(uint4*)(NB + (size_t)r*256 + c) = *(uint4*)o;
}

// ---------------- f16 MFMA GEMM, m97 structure: global_load_lds staged tiles ----------------
// C = bn(relu(A @ W[seg] + bias[seg])); A cols [0,KSPLIT) from A0, rest from A1.
// 128x128 tile per block, 4 waves 2x2, wave 64x64 = 4x4 frags.
// Per kb: block stages A-tile (8 KB, fragment-blob) + B-tile (8 KB, pre-packed blob)
// into LDS via 4 async global_load_lds/wave, then ds_read_b128 + 16 MFMA/wave.
template<int K, int KSPLIT, int LDA, int N, int NY, bool SEG>
__global__ __launch_bounds__(256)
void gemm_mfma(const f16_t* __restrict__ A0, const f16_t* __restrict__ A1,
               const f16_t* __restrict__ Wp,
               const float* __restrict__ bias,
               const float* __restrict__ bng, const float* __restrict__ bnb,
               const float* __restrict__ bnm, const float* __restrict__ bnv,
               f16_t* __restrict__ C)
{
    constexpr int NKB = K / 32;
    constexpr int NNT = N / 16;
    __shared__ char smem[17408];              // 16 KB staging  U  64x136 f16 epilogue
    f16_t* sA = (f16_t*)smem;                 // 8 chunks x 512 f16 (A fragment blobs)
    f16_t* sB = sA + 4096;                    // 8 chunks x 512 f16 (B blobs)
    f16_t* eps = (f16_t*)smem;                // epilogue overlay

    const int t = threadIdx.x;
    const int lane = t & 63, wave = t >> 6;
    const int wm = wave >> 1, wn = wave & 1;
    const int quad = lane >> 4, l16 = lane & 15;
    // XCD-aware remap (8 XCDs, round-robin dispatch heuristic)
    const int id = blockIdx.x;
    const int xcd = id & 7;
    const int jj = id >> 3;
    const int xi = jj / NY;
    const int y  = jj - xi * NY;
    const int r0 = (xi * 8 + xcd) * 128;
    const int n0 = y * 128;
    const int seg = SEG ? seg_of(r0) : 0;
    const int nbase = n0 >> 4;

    f32x4 acc[4][4];
#pragma unroll
    for (int mi = 0; mi < 4; ++mi)
#pragma unroll
        for (int ni = 0; ni < 4; ++ni) acc[mi][ni] = (f32x4){0.f,0.f,0.f,0.f};

    // per-lane A source offset for this wave's two staged chunks (mt = wave*2+i)
    size_t aoff[2];
#pragma unroll
    for (int i = 0; i < 2; ++i)
        aoff[i] = (size_t)(r0 + (wave*2 + i)*16 + l16) * LDA + quad*8;
    size_t bbase[2];
#pragma unroll
    for (int i = 0; i < 2; ++i)
        bbase[i] = ((size_t)(seg*NNT + nbase + wave*2 + i) * NKB) * 512 + lane*8;

#pragma unroll
    for (int kb = 0; kb < NKB; ++kb) {
        const int kg = kb * 32;
        const f16_t* Ab = (kg < KSPLIT) ? (A0 + kg) : (A1 + (kg - KSPLIT));
#pragma unroll
        for (int i = 0; i < 2; ++i) {
            glds16(Ab + aoff[i], sA + (wave*2 + i)*512);
            glds16(Wp + bbase[i] + (size_t)kb*512, sB + (wave*2 + i)*512);
        }
        __syncthreads();
        half8 a[4], b[4];
#pragma unroll
        for (int mi = 0; mi < 4; ++mi)
            a[mi] = *(const half8*)(sA + (wm*4 + mi)*512 + lane*8);
#pragma unroll
        for (int ni = 0; ni < 4; ++ni)
            b[ni] = *(const half8*)(sB + (wn*4 + ni)*512 + lane*8);
#pragma unroll
        for (int mi = 0; mi < 4; ++mi)
#pragma unroll
            for (int ni = 0; ni < 4; ++ni)
                acc[mi][ni] = __builtin_amdgcn_mfma_f32_16x16x32_f16(a[mi], b[ni], acc[mi][ni], 0, 0, 0);
        __syncthreads();
    }

    // epilogue, two 64-row passes through the 17.4 KB LDS overlay
#pragma unroll
    for (int p = 0; p < 2; ++p) {
        if (wm == p) {
#pragma unroll
            for (int ni = 0; ni < 4; ++ni) {
                const int lcol = (wn*4 + ni)*16 + l16;
                const int col = n0 + lcol;
                const float scale = bng[col] * rsqrtf(bnv[col] + 1e-3f);
                const float shift = bnb[col] - bnm[col] * scale;
                const float bv = bias[(SEG ? seg*N : 0) + col];
#pragma unroll
                for (int mi = 0; mi < 4; ++mi) {
                    const int lrowb = mi*16 + quad*4;
#pragma unroll
                    for (int r = 0; r < 4; ++r) {
                        float v = acc[mi][ni][r] + bv;
                        v = fmaxf(v, 0.f);
                        v = fmaf(v, scale, shift);
                        eps[(lrowb + r)*136 + lcol] = (f16_t)v;
                    }
                }
            }
        }
        __syncthreads();
#pragma unroll
        for (int it = 0; it < 4; ++it) {
            int row = it*16 + (t >> 4);
            int ch  = t & 15;
            uint4 v = *(const uint4*)&eps[row*136 + ch*8];
            *(uint4*)(C + (size_t)(r0 + p*64 + row)*N + n0 + ch*8) = v;
        }
        __syncthreads();
    }
}

// ---------------- segment scatter (each segment has exactly 32 atoms) ----------------
__global__ void scatter_k(const int* __restrict__ mem, int* __restrict__ counts, int* __restrict__ slots) {
    int i = blockIdx.x * 256 + threadIdx.x;   // 65536 exact
    int s = mem[i];
    int p = atomicAdd(&counts[s], 1);
    if (p < 32) slots[s*32 + p] = i;
}

// ---------------- segment sum/max over H3[65536x512] f16 -> fp = tanh([ssum|smax]) ----------------
__global__ __launch_bounds__(256)
void reduce_k(const f16_t* __restrict__ H3, const int* __restrict__ slots, float* __restrict__ fp) {
    int s = blockIdx.x, t = threadIdx.x;
    const int* sl = slots + s*32;
    float s0 = 0.f, s1 = 0.f, m0 = -INFINITY, m1 = -INFINITY;
#pragma unroll
    for (int i = 0; i < 32; i += 4) {
        int a[4];
#pragma unroll
        for (int j = 0; j < 4; ++j) a[j] = sl[i+j];
        float v0[4], v1[4];
#pragma unroll
        for (int j = 0; j < 4; ++j) {
            const f16_t* hr = H3 + (size_t)a[j]*512;
            v0[j] = (float)hr[t]; v1[j] = (float)hr[t+256];
        }
#pragma unroll
        for (int j = 0; j < 4; ++j) {
            s0 += v0[j]; s1 += v1[j];
            m0 = fmaxf(m0, v0[j]); m1 = fmaxf(m1, v1[j]);
        }
    }
    float* fr = fp + (size_t)s*1024;
    fr[t]       = tanhf(s0);
    fr[t+256]   = tanhf(s1);
    fr[512+t]   = tanhf(m0);
    fr[768+t]   = tanhf(m1);
}

// ---------------- logits = fp @ out_w + out_b; probs = softmax(pairs) ----------------
__global__ __launch_bounds__(256)
void final_k(const float* __restrict__ fp, const float* __restrict__ out_w,
             const float* __restrict__ out_b, float* __restrict__ probs, float* __restrict__ logits) {
    __shared__ float row[1024];
    __shared__ float lg[24];
    int s = blockIdx.x, t = threadIdx.x;
    const float* fr = fp + (size_t)s*1024;
    *(float4*)&row[t*4] = *(const float4*)&fr[t*4];
    __syncthreads();
    if (t < 192) {
        int o = t >> 3;
        int k0 = (t & 7) * 128;
        float acc = 0.f;
        for (int k = 0; k < 128; ++k)
            acc = fmaf(row[k0+k], out_w[(size_t)(k0+k)*24 + o], acc);
        acc += __shfl_xor(acc, 1);
        acc += __shfl_xor(acc, 2);
        acc += __shfl_xor(acc, 4);
        if ((t & 7) == 0) lg[o] = acc + out_b[o];
    }
    __syncthreads();
    if (t < 12) {
        float l0 = lg[2*t], l1 = lg[2*t+1];
        float m = fmaxf(l0, l1);
        float e0 = expf(l0-m), e1 = expf(l1-m);
        float inv = 1.f / (e0 + e1);
        int base = s*24 + 2*t;
        probs[base]   = e0*inv;  probs[base+1]  = e1*inv;
        logits[base]  = l0;      logits[base+1] = l1;
    }
}

extern "C" void kernel_launch(void* const* d_in, const int* in_sizes, int n_in,
                              void* d_out, int out_size, void* d_ws, size_t ws_size,
                              hipStream_t stream) {
    const float* atom       = (const float*)d_in[0];
    const int*   membership = (const int*)  d_in[2];
    Adj adj;
    for (int d = 0; d < 10; ++d) adj.p[d] = (const int*)d_in[4+d];
    const float* gc1_w0     = (const float*)d_in[14];
    const float* gc1_wself  = (const float*)d_in[15];
    const float* gc1_wneigh = (const float*)d_in[16];
    const float* gc1_b      = (const float*)d_in[17];
    const float* gc2_w0     = (const float*)d_in[18];
    const float* gc2_wself  = (const float*)d_in[19];
    const float* gc2_wneigh = (const float*)d_in[20];
    const float* gc2_b      = (const float*)d_in[21];
    const float* bn1g = (const float*)d_in[22]; const float* bn1b = (const float*)d_in[23];
    const float* bn1m = (const float*)d_in[24]; const float* bn1v = (const float*)d_in[25];
    const float* bn2g = (const float*)d_in[26]; const float* bn2b = (const float*)d_in[27];
    const float* bn2m = (const float*)d_in[28]; const float* bn2v = (const float*)d_in[29];
    const float* bn3g = (const float*)d_in[30]; const float* bn3b = (const float*)d_in[31];
    const float* bn3m = (const float*)d_in[32]; const float* bn3v = (const float*)d_in[33];
    const float* dense_w = (const float*)d_in[34];
    const float* dense_b = (const float*)d_in[35];
    const float* out_w   = (const float*)d_in[36];
    const float* out_b   = (const float*)d_in[37];

    // workspace layout in f16 elements (2 B each); aliasing:
    //   H2 = H1; P2 = NB2 slot; H3 = H1+P1 span (all dead by their reuse points)
    f16_t* wsb = (f16_t*)d_ws;
    f16_t* xq   = wsb;                       //  6,291,456
    f16_t* NBX  = wsb + 6291456;             //  6,291,456
    f16_t* H1b  = wsb + 12582912;            // 16,777,216
    f16_t* P1b  = wsb + 29360128;            // 16,777,216
    f16_t* NB2b = wsb + 46137344;            // 16,777,216
    f16_t* H2b  = H1b;
    f16_t* P2b  = NB2b;
    f16_t* H3b  = H1b;                       // 33,554,432 spans H1+P1
    f16_t* W1p  = wsb + 62914560;            //    540,672
    f16_t* W2p  = wsb + 63455232;            //  1,441,792
    f16_t* Wdp  = wsb + 64897024;            //    131,072
    int*  counts = (int*)(wsb + 65028096);   // 2048 ints
    int*  slots  = counts + 2048;            // 65536 ints

    float* outp   = (float*)d_out;
    float* probs  = outp;            // 2048*24
    float* logits = outp + 49152;    // 2048*24
    float* fp     = outp + 98304;    // 2048*1024

    // weight packing
    pack_w1<<<2112, 256, 0, stream>>>(gc1_w0, gc1_wself, gc1_wneigh, W1p);
    pack_w2<<<5632, 256, 0, stream>>>(gc2_w0, gc2_wself, gc2_wneigh, W2p);
    pack_wd<<<512,  256, 0, stream>>>(dense_w, Wdp);

    // gc1: xq (self, k<96) + NBX (neigh, k>=96)
    cvt_pad<<<(NATOMS*96)/256, 256, 0, stream>>>(atom, xq);
    nbsum_x<<<(NATOMS*16)/256, 256, 0, stream>>>(xq, NBX, adj);
    gemm_mfma<192,96,96,256,2,true><<<1024, 256, 0, stream>>>(
        xq, NBX, W1p, gc1_b, bn1g, bn1b, bn1m, bn1v, H1b);
    pool_k<<<(NATOMS*32)/256, 256, 0, stream>>>(H1b, P1b, adj);

    // gc2
    nbsum_k<<<(NATOMS*32)/256, 256, 0, stream>>>(P1b, NB2b, adj);
    gemm_mfma<512,256,256,256,2,true><<<1024, 256, 0, stream>>>(
        P1b, NB2b, W2p, gc2_b, bn2g, bn2b, bn2m, bn2v, H2b);
    pool_k<<<(NATOMS*32)/256, 256, 0, stream>>>(H2b, P2b, adj);

    // dense
    gemm_mfma<256,256,256,512,4,false><<<2048, 256, 0, stream>>>(
        P2b, P2b, Wdp, dense_b, bn3g, bn3b, bn3m, bn3v, H3b);

    // segment reduce + tanh -> fp
    hipMemsetAsync((void*)counts, 0, 2048*sizeof(int), stream);
    scatter_k<<<NATOMS/256, 256, 0, stream>>>(membership, counts, slots);
    reduce_k<<<2048, 256, 0, stream>>>(H3b, slots, fp);

    // readout
    final_k<<<2048, 256, 0, stream>>>(fp, out_w, out_b, probs, logits);
}

// Round 8
// 385.367 us; speedup vs baseline: 1.2257x; 1.0146x over previous
//
#include <hip/hip_runtime.h>
#include <hip/hip_fp16.h>
#include <math.h>

#define NATOMS 65536

typedef _Float16 f16_t;
typedef __attribute__((ext_vector_type(8))) _Float16 half8;
typedef __attribute__((ext_vector_type(4))) float f32x4;

__constant__ int c_offs[12] = {0,1536,9728,26112,50688,62976,64000,64512,65024,65280,65408,65536};

struct Adj { const int* p[10]; };

__device__ __forceinline__ int seg_of(int row) {
    int s = 0;
#pragma unroll
    for (int i = 1; i <= 10; ++i) s += (row >= c_offs[i]) ? 1 : 0;
    return s;
}

// async global -> LDS, 16 B per lane; LDS dst = wave-uniform base + lane*16
__device__ __forceinline__ void glds16(const f16_t* g, f16_t* l) {
    __builtin_amdgcn_global_load_lds(
        (const __attribute__((address_space(1))) unsigned int*)g,
        (__attribute__((address_space(3))) unsigned int*)l,
        16, 0, 0);
}

// ---------------- weight packing into MFMA B-fragment layout ----------------
// blob index: (((seg*NNT + ni)*NKB + kb)*512) + lane*8 + j
// blob[lane][j] = W[kb*32 + (lane>>4)*8 + j][ni*16 + (lane&15)]

__global__ void pack_w1(const float* __restrict__ w0, const float* __restrict__ wself,
                        const float* __restrict__ wneigh, f16_t* __restrict__ Wp) {
    int idx = blockIdx.x * 256 + threadIdx.x;      // 11*16*6*512 = 540672 exact
    int j = idx & 7, lane = (idx >> 3) & 63;
    int kb = (idx >> 9) % 6;
    int rest = idx / (512 * 6);
    int ni = rest & 15, s = rest >> 4;
    int k = kb * 32 + (lane >> 4) * 8 + j;
    int n = ni * 16 + (lane & 15);
    float v = 0.f;
    if (k < 75) v = (s == 0) ? w0[k*256 + n] : wself[((s-1)*75 + k)*256 + n];
    else if (k >= 96 && k < 171 && s > 0) v = wneigh[((s-1)*75 + (k-96))*256 + n];
    Wp[idx] = (f16_t)v;
}

__global__ void pack_w2(const float* __restrict__ w0, const float* __restrict__ wself,
                        const float* __restrict__ wneigh, f16_t* __restrict__ Wp) {
    int idx = blockIdx.x * 256 + threadIdx.x;      // 11*16*16*512 = 1441792 exact
    int j = idx & 7, lane = (idx >> 3) & 63;
    int kb = (idx >> 9) & 15;
    int rest = idx >> 13;
    int ni = rest & 15, s = rest >> 4;
    int k = kb * 32 + (lane >> 4) * 8 + j;
    int n = ni * 16 + (lane & 15);
    float v = 0.f;
    if (k < 256) v = (s == 0) ? w0[k*256 + n] : wself[((s-1)*256 + k)*256 + n];
    else if (s > 0) v = wneigh[((s-1)*256 + (k-256))*256 + n];
    Wp[idx] = (f16_t)v;
}

__global__ void pack_wd(const float* __restrict__ w, f16_t* __restrict__ Wp) {
    int idx = blockIdx.x * 256 + threadIdx.x;      // 32*8*512 = 131072 exact
    int j = idx & 7, lane = (idx >> 3) & 63;
    int kb = (idx >> 9) & 7;
    int ni = (idx >> 12) & 31;
    int k = kb * 32 + (lane >> 4) * 8 + j;
    int n = ni * 16 + (lane & 15);
    Wp[idx] = (f16_t)w[(size_t)k*512 + n];
}

// out_w[1024][24] -> blob [2][32][512], n>=24 zero-padded
__global__ void pack_wo(const float* __restrict__ w, f16_t* __restrict__ Wp) {
    int idx = blockIdx.x * 256 + threadIdx.x;      // 2*32*512 = 32768 exact
    int j = idx & 7, lane = (idx >> 3) & 63;
    int kb = (idx >> 9) & 31;
    int ni = idx >> 14;
    int k = kb * 32 + (lane >> 4) * 8 + j;
    int n = ni * 16 + (lane & 15);
    Wp[idx] = (n < 24) ? (f16_t)w[k*24 + n] : (f16_t)0.f;
}

// ---------------- xq = f16(atom_features) padded 75 -> 96 cols ----------------
__global__ void cvt_pad(const float* __restrict__ xf, f16_t* __restrict__ xq) {
    int idx = blockIdx.x * 256 + threadIdx.x;   // 65536*96 exact
    int r = idx / 96;
    int c = idx - r * 96;
    xq[idx] = (c < 75) ? (f16_t)xf[(size_t)r*75 + c] : (f16_t)0.f;
}

// ---------------- compile-time-degree gather helpers ----------------
template<int D, bool ISMAX, int LD>
__device__ __forceinline__ void gathD(float* v, const f16_t* __restrict__ src,
                                      const int* __restrict__ ap, int c) {
    int rows[D];
#pragma unroll
    for (int j = 0; j < D; ++j) rows[j] = ap[j];
    uint4 raw[D];
#pragma unroll
    for (int j = 0; j < D; ++j) raw[j] = *(const uint4*)(src + (size_t)rows[j]*LD + c);
#pragma unroll
    for (int j = 0; j < D; ++j) {
        const f16_t* u = (const f16_t*)&raw[j];
#pragma unroll
        for (int e = 0; e < 8; ++e) {
            float f = (float)u[e];
            v[e] = ISMAX ? fmaxf(v[e], f) : (v[e] + f);
        }
    }
}

template<bool ISMAX, int LD>
__device__ __forceinline__ void gath_switch(float* v, const f16_t* __restrict__ src,
                                            const int* __restrict__ ap, int s, int c) {
    switch (s) {   // per-block uniform (segment boundaries are multiples of 128)
        case 1:  gathD<1,ISMAX,LD>(v,src,ap,c);  break;
        case 2:  gathD<2,ISMAX,LD>(v,src,ap,c);  break;
        case 3:  gathD<3,ISMAX,LD>(v,src,ap,c);  break;
        case 4:  gathD<4,ISMAX,LD>(v,src,ap,c);  break;
        case 5:  gathD<5,ISMAX,LD>(v,src,ap,c);  break;
        case 6:  gathD<6,ISMAX,LD>(v,src,ap,c);  break;
        case 7:  gathD<7,ISMAX,LD>(v,src,ap,c);  break;
        case 8:  gathD<8,ISMAX,LD>(v,src,ap,c);  break;
        case 9:  gathD<9,ISMAX,LD>(v,src,ap,c);  break;
        case 10: gathD<10,ISMAX,LD>(v,src,ap,c); break;
        default: break;
    }
}

// ---------------- NBX[r] = sum_neigh xq, 96 cols ----------------
__global__ __launch_bounds__(256) void nbsum_x(const f16_t* __restrict__ xq, f16_t* __restrict__ NBX, Adj adj) {
    int idx = blockIdx.x * 256 + threadIdx.x;   // 65536*16 exact, cc>=12 idle
    int r = idx >> 4;
    int cc = idx & 15;
    if (cc >= 12) return;
    int c = cc << 3;
    int s = seg_of(r);
    float v[8];
#pragma unroll
    for (int e = 0; e < 8; ++e) v[e] = 0.f;
    if (s > 0)
        gath_switch<false,96>(v, xq, adj.p[s-1] + (size_t)(r - c_offs[s]) * s, s, c);
    f16_t o[8];
#pragma unroll
    for (int e = 0; e < 8; ++e) o[e] = (f16_t)v[e];
    *(uint4*)(NBX + (size_t)r*96 + c) = *(uint4*)o;
}

// ---------------- graph pool: elementwise max over self+neighbors ----------------
__global__ __launch_bounds__(256) void pool_k(const f16_t* __restrict__ H, f16_t* __restrict__ P, Adj adj) {
    int idx = blockIdx.x * 256 + threadIdx.x;   // 65536*32 exact
    int r = idx >> 5;
    int c = (idx & 31) << 3;
    int s = seg_of(r);
    uint4 self = *(const uint4*)(H + (size_t)r*256 + c);
    const f16_t* hp = (const f16_t*)&self;
    float v[8];
#pragma unroll
    for (int e = 0; e < 8; ++e) v[e] = (float)hp[e];
    if (s > 0)
        gath_switch<true,256>(v, H, adj.p[s-1] + (size_t)(r - c_offs[s]) * s, s, c);
    f16_t o[8];
#pragma unroll
    for (int e = 0; e < 8; ++e) o[e] = (f16_t)v[e];
    *(uint4*)(P + (size_t)r*256 + c) = *(uint4*)o;
}

// ---------------- neighbor-sum of pooled features, 256 cols ----------------
__global__ __launch_bounds__(256) void nbsum_k(const f16_t* __restrict__ P, f16_t* __restrict__ NB, Adj adj) {
    int idx = blockIdx.x * 256 + threadIdx.x;   // 65536*32 exact
    int r = idx >> 5;
    int c = (idx & 31) << 3;
    int s = seg_of(r);
    float v[8];
#pragma unroll
    for (int e = 0; e < 8; ++e) v[e] = 0.f;
    if (s > 0)
        gath_switch<false,256>(v, P, adj.p[s-1] + (size_t)(r - c_offs[s]) * s, s, c);
    f16_t o[8];
#pragma unroll
    for (int e = 0; e < 8; ++e) o[e] = (f16_t)v[e];
    *(uint4*)(NB + (size_t)r*256 + c) = *(uint4*)o;
}

// ---------------- f16 MFMA GEMM, m97 structure: global_load_lds staged tiles ----------------
template<int K, int KSPLIT, int LDA, int N, int NY, bool SEG>
__global__ __launch_bounds__(256)
void gemm_mfma(const f16_t* __restrict__ A0, const f16_t* __restrict__ A1,
               const f16_t* __restrict__ Wp,
               const float* __restrict__ bias,
               const float* __restrict__ bng, const float* __restrict__ bnb,
               const float* __restrict__ bnm, const float* __restrict__ bnv,
               f16_t* __restrict__ C)
{
    constexpr int NKB = K / 32;
    constexpr int NNT = N / 16;
    __shared__ char smem[17408];              // 16 KB staging  U  64x136 f16 epilogue
    f16_t* sA = (f16_t*)smem;                 // 8 chunks x 512 f16 (A fragment blobs)
    f16_t* sB = sA + 4096;                    // 8 chunks x 512 f16 (B blobs)
    f16_t* eps = (f16_t*)smem;                // epilogue overlay

    const int t = threadIdx.x;
    const int lane = t & 63, wave = t >> 6;
    const int wm = wave >> 1, wn = wave & 1;
    const int quad = lane >> 4, l16 = lane & 15;
    const int id = blockIdx.x;
    const int xcd = id & 7;
    const int jj = id >> 3;
    const int xi = jj / NY;
    const int y  = jj - xi * NY;
    const int r0 = (xi * 8 + xcd) * 128;
    const int n0 = y * 128;
    const int seg = SEG ? seg_of(r0) : 0;
    const int nbase = n0 >> 4;

    f32x4 acc[4][4];
#pragma unroll
    for (int mi = 0; mi < 4; ++mi)
#pragma unroll
        for (int ni = 0; ni < 4; ++ni) acc[mi][ni] = (f32x4){0.f,0.f,0.f,0.f};

    size_t aoff[2];
#pragma unroll
    for (int i = 0; i < 2; ++i)
        aoff[i] = (size_t)(r0 + (wave*2 + i)*16 + l16) * LDA + quad*8;
    size_t bbase[2];
#pragma unroll
    for (int i = 0; i < 2; ++i)
        bbase[i] = ((size_t)(seg*NNT + nbase + wave*2 + i) * NKB) * 512 + lane*8;

#pragma unroll
    for (int kb = 0; kb < NKB; ++kb) {
        const int kg = kb * 32;
        const f16_t* Ab = (kg < KSPLIT) ? (A0 + kg) : (A1 + (kg - KSPLIT));
#pragma unroll
        for (int i = 0; i < 2; ++i) {
            glds16(Ab + aoff[i], sA + (wave*2 + i)*512);
            glds16(Wp + bbase[i] + (size_t)kb*512, sB + (wave*2 + i)*512);
        }
        __syncthreads();
        half8 a[4], b[4];
#pragma unroll
        for (int mi = 0; mi < 4; ++mi)
            a[mi] = *(const half8*)(sA + (wm*4 + mi)*512 + lane*8);
#pragma unroll
        for (int ni = 0; ni < 4; ++ni)
            b[ni] = *(const half8*)(sB + (wn*4 + ni)*512 + lane*8);
#pragma unroll
        for (int mi = 0; mi < 4; ++mi)
#pragma unroll
            for (int ni = 0; ni < 4; ++ni)
                acc[mi][ni] = __builtin_amdgcn_mfma_f32_16x16x32_f16(a[mi], b[ni], acc[mi][ni], 0, 0, 0);
        __syncthreads();
    }

    // epilogue, two 64-row passes through the 17.4 KB LDS overlay
#pragma unroll
    for (int p = 0; p < 2; ++p) {
        if (wm == p) {
#pragma unroll
            for (int ni = 0; ni < 4; ++ni) {
                const int lcol = (wn*4 + ni)*16 + l16;
                const int col = n0 + lcol;
                const float scale = bng[col] * rsqrtf(bnv[col] + 1e-3f);
                const float shift = bnb[col] - bnm[col] * scale;
                const float bv = bias[(SEG ? seg*N : 0) + col];
#pragma unroll
                for (int mi = 0; mi < 4; ++mi) {
                    const int lrowb = mi*16 + quad*4;
#pragma unroll
                    for (int r = 0; r < 4; ++r) {
                        float v = acc[mi][ni][r] + bv;
                        v = fmaxf(v, 0.f);
                        v = fmaf(v, scale, shift);
                        eps[(lrowb + r)*136 + lcol] = (f16_t)v;
                    }
                }
            }
        }
        __syncthreads();
#pragma unroll
        for (int it = 0; it < 4; ++it) {
            int row = it*16 + (t >> 4);
            int ch  = t & 15;
            uint4 v = *(const uint4*)&eps[row*136 + ch*8];
            *(uint4*)(C + (size_t)(r0 + p*64 + row)*N + n0 + ch*8) = v;
        }
        __syncthreads();
    }
}

// ---------------- segment scatter (each segment has exactly 32 atoms) ----------------
__global__ void scatter_k(const int* __restrict__ mem, int* __restrict__ counts, int* __restrict__ slots) {
    int i = blockIdx.x * 256 + threadIdx.x;   // 65536 exact
    int s = mem[i];
    int p = atomicAdd(&counts[s], 1);
    if (p < 32) slots[s*32 + p] = i;
}

// ---------------- segment sum/max over H3[65536x512] -> fp = tanh([ssum|smax]) ----------------
// one wave per segment; lane l owns cols [l*8, l*8+8); 32 coalesced 1-KB row reads
__global__ __launch_bounds__(64)
void reduce_k(const f16_t* __restrict__ H3, const int* __restrict__ slots,
              float* __restrict__ fp, f16_t* __restrict__ fph) {
    int s = blockIdx.x, l = threadIdx.x;
    int c = l * 8;
    const int* sl = slots + s*32;
    float sm[8], mx[8];
#pragma unroll
    for (int e = 0; e < 8; ++e) { sm[e] = 0.f; mx[e] = -INFINITY; }
#pragma unroll
    for (int i = 0; i < 32; ++i) {
        int a = sl[i];
        uint4 raw = *(const uint4*)(H3 + (size_t)a*512 + c);
        const f16_t* u = (const f16_t*)&raw;
#pragma unroll
        for (int e = 0; e < 8; ++e) {
            float f = (float)u[e];
            sm[e] += f;
            mx[e] = fmaxf(mx[e], f);
        }
    }
    float o1[8], o2[8];
    f16_t h1[8], h2[8];
#pragma unroll
    for (int e = 0; e < 8; ++e) {
        o1[e] = tanhf(sm[e]); o2[e] = tanhf(mx[e]);
        h1[e] = (f16_t)o1[e]; h2[e] = (f16_t)o2[e];
    }
    float* fr = fp + (size_t)s*1024;
    *(float4*)(fr + c)       = *(float4*)&o1[0];
    *(float4*)(fr + c + 4)   = *(float4*)&o1[4];
    *(float4*)(fr + 512 + c)     = *(float4*)&o2[0];
    *(float4*)(fr + 512 + c + 4) = *(float4*)&o2[4];
    f16_t* fh = fph + (size_t)s*1024;
    *(uint4*)(fh + c)       = *(uint4*)h1;
    *(uint4*)(fh + 512 + c) = *(uint4*)h2;
}

// ---------------- readout GEMM: logits = fph @ out_w + out_b; probs = pair-softmax ----------------
// M=2048, K=1024, N=32 (cols 24..31 zero-padded). 8 blocks x 4 waves x 64 rows.
__global__ __launch_bounds__(256)
void final_mfma(const f16_t* __restrict__ fph, const f16_t* __restrict__ Wop,
                const float* __restrict__ out_b,
                float* __restrict__ probs, float* __restrict__ logits) {
    const int t = threadIdx.x;
    const int lane = t & 63, wave = t >> 6;
    const int quad = lane >> 4, l16 = lane & 15;
    const int r0 = blockIdx.x * 256 + wave * 64;

    f32x4 acc[4][2];
#pragma unroll
    for (int mi = 0; mi < 4; ++mi)
#pragma unroll
        for (int ni = 0; ni < 2; ++ni) acc[mi][ni] = (f32x4){0.f,0.f,0.f,0.f};

    size_t rowoff[4];
#pragma unroll
    for (int mi = 0; mi < 4; ++mi)
        rowoff[mi] = (size_t)(r0 + mi*16 + l16) * 1024 + quad*8;
    size_t boff[2];
#pragma unroll
    for (int ni = 0; ni < 2; ++ni)
        boff[ni] = (size_t)ni * 32 * 512 + lane*8;

    auto loadA = [&](half8* a, int kb) {
#pragma unroll
        for (int mi = 0; mi < 4; ++mi) a[mi] = *(const half8*)(fph + rowoff[mi] + kb*32);
    };
    auto loadB = [&](half8* b, int kb) {
#pragma unroll
        for (int ni = 0; ni < 2; ++ni) b[ni] = *(const half8*)(Wop + boff[ni] + (size_t)kb*512);
    };
    auto domfma = [&](half8* a, half8* b) {
#pragma unroll
        for (int mi = 0; mi < 4; ++mi)
#pragma unroll
            for (int ni = 0; ni < 2; ++ni)
                acc[mi][ni] = __builtin_amdgcn_mfma_f32_16x16x32_f16(a[mi], b[ni], acc[mi][ni], 0, 0, 0);
    };

    half8 a0[4], b0[2], a1[4], b1[2];
    loadA(a0, 0); loadB(b0, 0);
#pragma unroll
    for (int kb = 0; kb < 32; kb += 2) {
        loadA(a1, kb + 1); loadB(b1, kb + 1);
        domfma(a0, b0);
        if (kb + 2 < 32) { loadA(a0, kb + 2); loadB(b0, kb + 2); }
        domfma(a1, b1);
    }

    // epilogue: lane holds col c = ni*16 + l16, rows quad*4 + r; pair partner via shfl_xor(1)
#pragma unroll
    for (int ni = 0; ni < 2; ++ni) {
        const int c = ni*16 + l16;
        const bool ok = (c < 24);
        const float bv = ok ? out_b[c] : 0.f;
#pragma unroll
        for (int mi = 0; mi < 4; ++mi) {
#pragma unroll
            for (int r = 0; r < 4; ++r) {
                float lg = acc[mi][ni][r] + bv;
                float lp = __shfl_xor(lg, 1);
                float m = fmaxf(lg, lp);
                float e  = expf(lg - m);
                float ep = expf(lp - m);
                float pr = e / (e + ep);
                if (ok) {
                    int row = r0 + mi*16 + quad*4 + r;
                    logits[(size_t)row*24 + c] = lg;
                    probs[(size_t)row*24 + c]  = pr;
                }
            }
        }
    }
}

extern "C" void kernel_launch(void* const* d_in, const int* in_sizes, int n_in,
                              void* d_out, int out_size, void* d_ws, size_t ws_size,
                              hipStream_t stream) {
    const float* atom       = (const float*)d_in[0];
    const int*   membership = (const int*)  d_in[2];
    Adj adj;
    for (int d = 0; d < 10; ++d) adj.p[d] = (const int*)d_in[4+d];
    const float* gc1_w0     = (const float*)d_in[14];
    const float* gc1_wself  = (const float*)d_in[15];
    const float* gc1_wneigh = (const float*)d_in[16];
    const float* gc1_b      = (const float*)d_in[17];
    const float* gc2_w0     = (const float*)d_in[18];
    const float* gc2_wself  = (const float*)d_in[19];
    const float* gc2_wneigh = (const float*)d_in[20];
    const float* gc2_b      = (const float*)d_in[21];
    const float* bn1g = (const float*)d_in[22]; const float* bn1b = (const float*)d_in[23];
    const float* bn1m = (const float*)d_in[24]; const float* bn1v = (const float*)d_in[25];
    const float* bn2g = (const float*)d_in[26]; const float* bn2b = (const float*)d_in[27];
    const float* bn2m = (const float*)d_in[28]; const float* bn2v = (const float*)d_in[29];
    const float* bn3g = (const float*)d_in[30]; const float* bn3b = (const float*)d_in[31];
    const float* bn3m = (const float*)d_in[32]; const float* bn3v = (const float*)d_in[33];
    const float* dense_w = (const float*)d_in[34];
    const float* dense_b = (const float*)d_in[35];
    const float* out_w   = (const float*)d_in[36];
    const float* out_b   = (const float*)d_in[37];

    // workspace layout in f16 elements (2 B each)
    f16_t* wsb = (f16_t*)d_ws;
    f16_t* xq   = wsb;                       //  6,291,456
    f16_t* NBX  = wsb + 6291456;             //  6,291,456
    f16_t* H1b  = wsb + 12582912;            // 16,777,216
    f16_t* P1b  = wsb + 29360128;            // 16,777,216
    f16_t* NB2b = wsb + 46137344;            // 16,777,216
    f16_t* H2b  = H1b;
    f16_t* P2b  = NB2b;
    f16_t* H3b  = H1b;                       // 33,554,432 spans H1+P1
    f16_t* W1p  = wsb + 62914560;            //    540,672
    f16_t* W2p  = wsb + 63455232;            //  1,441,792
    f16_t* Wdp  = wsb + 64897024;            //    131,072
    f16_t* fph  = wsb + 65028096;            //  2,097,152 (2048x1024 f16)
    f16_t* Wop  = wsb + 67125248;            //     32,768
    int*  counts = (int*)(wsb + 67158016);   // 2048 ints
    int*  slots  = counts + 2048;            // 65536 ints

    float* outp   = (float*)d_out;
    float* probs  = outp;            // 2048*24
    float* logits = outp + 49152;    // 2048*24
    float* fp     = outp + 98304;    // 2048*1024

    // weight packing
    pack_w1<<<2112, 256, 0, stream>>>(gc1_w0, gc1_wself, gc1_wneigh, W1p);
    pack_w2<<<5632, 256, 0, stream>>>(gc2_w0, gc2_wself, gc2_wneigh, W2p);
    pack_wd<<<512,  256, 0, stream>>>(dense_w, Wdp);
    pack_wo<<<128,  256, 0, stream>>>(out_w, Wop);

    // gc1: xq (self, k<96) + NBX (neigh, k>=96)
    cvt_pad<<<(NATOMS*96)/256, 256, 0, stream>>>(atom, xq);
    nbsum_x<<<(NATOMS*16)/256, 256, 0, stream>>>(xq, NBX, adj);
    gemm_mfma<192,96,96,256,2,true><<<1024, 256, 0, stream>>>(
        xq, NBX, W1p, gc1_b, bn1g, bn1b, bn1m, bn1v, H1b);
    pool_k<<<(NATOMS*32)/256, 256, 0, stream>>>(H1b, P1b, adj);

    // gc2
    nbsum_k<<<(NATOMS*32)/256, 256, 0, stream>>>(P1b, NB2b, adj);
    gemm_mfma<512,256,256,256,2,true><<<1024, 256, 0, stream>>>(
        P1b, NB2b, W2p, gc2_b, bn2g, bn2b, bn2m, bn2v, H2b);
    pool_k<<<(NATOMS*32)/256, 256, 0, stream>>>(H2b, P2b, adj);

    // dense
    gemm_mfma<256,256,256,512,4,false><<<2048, 256, 0, stream>>>(
        P2b, P2b, Wdp, dense_b, bn3g, bn3b, bn3m, bn3v, H3b);

    // segment reduce + tanh -> fp (fp32 to out) + fph (f16 to ws)
    hipMemsetAsync((void*)counts, 0, 2048*sizeof(int), stream);
    scatter_k<<<NATOMS/256, 256, 0, stream>>>(membership, counts, slots);
    reduce_k<<<2048, 64, 0, stream>>>(H3b, slots, fp, fph);

    // readout
    final_mfma<<<8, 256, 0, stream>>>(fph, Wop, out_b, probs, logits);
}

// Round 9
// 383.754 us; speedup vs baseline: 1.2308x; 1.0042x over previous
//
#include <hip/hip_runtime.h>
#include <hip/hip_fp16.h>
#include <math.h>

#define NATOMS 65536

typedef _Float16 f16_t;
typedef __attribute__((ext_vector_type(8))) _Float16 half8;
typedef __attribute__((ext_vector_type(4))) float f32x4;

__constant__ int c_offs[12] = {0,1536,9728,26112,50688,62976,64000,64512,65024,65280,65408,65536};

struct Adj { const int* p[10]; };

__device__ __forceinline__ int seg_of(int row) {
    int s = 0;
#pragma unroll
    for (int i = 1; i <= 10; ++i) s += (row >= c_offs[i]) ? 1 : 0;
    return s;
}

// async global -> LDS, 16 B per lane; LDS dst = wave-uniform base + lane*16
__device__ __forceinline__ void glds16(const f16_t* g, f16_t* l) {
    __builtin_amdgcn_global_load_lds(
        (const __attribute__((address_space(1))) unsigned int*)g,
        (__attribute__((address_space(3))) unsigned int*)l,
        16, 0, 0);
}

// ---------------- weight packing into MFMA B-fragment layout ----------------
// blob index: (((seg*NNT + ni)*NKB + kb)*512) + lane*8 + j
// blob[lane][j] = W[kb*32 + (lane>>4)*8 + j][ni*16 + (lane&15)]

__global__ void pack_w1(const float* __restrict__ w0, const float* __restrict__ wself,
                        const float* __restrict__ wneigh, f16_t* __restrict__ Wp) {
    int idx = blockIdx.x * 256 + threadIdx.x;      // 11*16*6*512 = 540672 exact
    int j = idx & 7, lane = (idx >> 3) & 63;
    int kb = (idx >> 9) % 6;
    int rest = idx / (512 * 6);
    int ni = rest & 15, s = rest >> 4;
    int k = kb * 32 + (lane >> 4) * 8 + j;
    int n = ni * 16 + (lane & 15);
    float v = 0.f;
    if (k < 75) v = (s == 0) ? w0[k*256 + n] : wself[((s-1)*75 + k)*256 + n];
    else if (k >= 96 && k < 171 && s > 0) v = wneigh[((s-1)*75 + (k-96))*256 + n];
    Wp[idx] = (f16_t)v;
}

__global__ void pack_w2(const float* __restrict__ w0, const float* __restrict__ wself,
                        const float* __restrict__ wneigh, f16_t* __restrict__ Wp) {
    int idx = blockIdx.x * 256 + threadIdx.x;      // 11*16*16*512 = 1441792 exact
    int j = idx & 7, lane = (idx >> 3) & 63;
    int kb = (idx >> 9) & 15;
    int rest = idx >> 13;
    int ni = rest & 15, s = rest >> 4;
    int k = kb * 32 + (lane >> 4) * 8 + j;
    int n = ni * 16 + (lane & 15);
    float v = 0.f;
    if (k < 256) v = (s == 0) ? w0[k*256 + n] : wself[((s-1)*256 + k)*256 + n];
    else if (s > 0) v = wneigh[((s-1)*256 + (k-256))*256 + n];
    Wp[idx] = (f16_t)v;
}

__global__ void pack_wd(const float* __restrict__ w, f16_t* __restrict__ Wp) {
    int idx = blockIdx.x * 256 + threadIdx.x;      // 32*8*512 = 131072 exact
    int j = idx & 7, lane = (idx >> 3) & 63;
    int kb = (idx >> 9) & 7;
    int ni = (idx >> 12) & 31;
    int k = kb * 32 + (lane >> 4) * 8 + j;
    int n = ni * 16 + (lane & 15);
    Wp[idx] = (f16_t)w[(size_t)k*512 + n];
}

// out_w[1024][24] -> blob [2][32][512], n>=24 zero-padded
__global__ void pack_wo(const float* __restrict__ w, f16_t* __restrict__ Wp) {
    int idx = blockIdx.x * 256 + threadIdx.x;      // 2*32*512 = 32768 exact
    int j = idx & 7, lane = (idx >> 3) & 63;
    int kb = (idx >> 9) & 31;
    int ni = idx >> 14;
    int k = kb * 32 + (lane >> 4) * 8 + j;
    int n = ni * 16 + (lane & 15);
    Wp[idx] = (n < 24) ? (f16_t)w[k*24 + n] : (f16_t)0.f;
}

// ---------------- xq = f16(atom_features) padded 75 -> 96 cols ----------------
__global__ void cvt_pad(const float* __restrict__ xf, f16_t* __restrict__ xq) {
    int idx = blockIdx.x * 256 + threadIdx.x;   // 65536*96 exact
    int r = idx / 96;
    int c = idx - r * 96;
    xq[idx] = (c < 75) ? (f16_t)xf[(size_t)r*75 + c] : (f16_t)0.f;
}

// ---------------- compile-time-degree gather helpers ----------------
template<int D, bool ISMAX, int LD>
__device__ __forceinline__ void gathD(float* v, const f16_t* __restrict__ src,
                                      const int* __restrict__ ap, int c) {
    int rows[D];
#pragma unroll
    for (int j = 0; j < D; ++j) rows[j] = ap[j];
    uint4 raw[D];
#pragma unroll
    for (int j = 0; j < D; ++j) raw[j] = *(const uint4*)(src + (size_t)rows[j]*LD + c);
#pragma unroll
    for (int j = 0; j < D; ++j) {
        const f16_t* u = (const f16_t*)&raw[j];
#pragma unroll
        for (int e = 0; e < 8; ++e) {
            float f = (float)u[e];
            v[e] = ISMAX ? fmaxf(v[e], f) : (v[e] + f);
        }
    }
}

template<bool ISMAX, int LD>
__device__ __forceinline__ void gath_switch(float* v, const f16_t* __restrict__ src,
                                            const int* __restrict__ ap, int s, int c) {
    switch (s) {   // per-block uniform (segment boundaries are multiples of 128)
        case 1:  gathD<1,ISMAX,LD>(v,src,ap,c);  break;
        case 2:  gathD<2,ISMAX,LD>(v,src,ap,c);  break;
        case 3:  gathD<3,ISMAX,LD>(v,src,ap,c);  break;
        case 4:  gathD<4,ISMAX,LD>(v,src,ap,c);  break;
        case 5:  gathD<5,ISMAX,LD>(v,src,ap,c);  break;
        case 6:  gathD<6,ISMAX,LD>(v,src,ap,c);  break;
        case 7:  gathD<7,ISMAX,LD>(v,src,ap,c);  break;
        case 8:  gathD<8,ISMAX,LD>(v,src,ap,c);  break;
        case 9:  gathD<9,ISMAX,LD>(v,src,ap,c);  break;
        case 10: gathD<10,ISMAX,LD>(v,src,ap,c); break;
        default: break;
    }
}

// ---------------- NBX[r] = sum_neigh xq, 96 cols ----------------
__global__ __launch_bounds__(256) void nbsum_x(const f16_t* __restrict__ xq, f16_t* __restrict__ NBX, Adj adj) {
    int idx = blockIdx.x * 256 + threadIdx.x;   // 65536*16 exact, cc>=12 idle
    int r = idx >> 4;
    int cc = idx & 15;
    if (cc >= 12) return;
    int c = cc << 3;
    int s = seg_of(r);
    float v[8];
#pragma unroll
    for (int e = 0; e < 8; ++e) v[e] = 0.f;
    if (s > 0)
        gath_switch<false,96>(v, xq, adj.p[s-1] + (size_t)(r - c_offs[s]) * s, s, c);
    f16_t o[8];
#pragma unroll
    for (int e = 0; e < 8; ++e) o[e] = (f16_t)v[e];
    *(uint4*)(NBX + (size_t)r*96 + c) = *(uint4*)o;
}

// ---------------- graph pool: elementwise max over self+neighbors ----------------
__global__ __launch_bounds__(256) void pool_k(const f16_t* __restrict__ H, f16_t* __restrict__ P, Adj adj) {
    int idx = blockIdx.x * 256 + threadIdx.x;   // 65536*32 exact
    int r = idx >> 5;
    int c = (idx & 31) << 3;
    int s = seg_of(r);
    uint4 self = *(const uint4*)(H + (size_t)r*256 + c);
    const f16_t* hp = (const f16_t*)&self;
    float v[8];
#pragma unroll
    for (int e = 0; e < 8; ++e) v[e] = (float)hp[e];
    if (s > 0)
        gath_switch<true,256>(v, H, adj.p[s-1] + (size_t)(r - c_offs[s]) * s, s, c);
    f16_t o[8];
#pragma unroll
    for (int e = 0; e < 8; ++e) o[e] = (f16_t)v[e];
    *(uint4*)(P + (size_t)r*256 + c) = *(uint4*)o;
}

// ---------------- neighbor-sum of pooled features, 256 cols ----------------
__global__ __launch_bounds__(256) void nbsum_k(const f16_t* __restrict__ P, f16_t* __restrict__ NB, Adj adj) {
    int idx = blockIdx.x * 256 + threadIdx.x;   // 65536*32 exact
    int r = idx >> 5;
    int c = (idx & 31) << 3;
    int s = seg_of(r);
    float v[8];
#pragma unroll
    for (int e = 0; e < 8; ++e) v[e] = 0.f;
    if (s > 0)
        gath_switch<false,256>(v, P, adj.p[s-1] + (size_t)(r - c_offs[s]) * s, s, c);
    f16_t o[8];
#pragma unroll
    for (int e = 0; e < 8; ++e) o[e] = (f16_t)v[e];
    *(uint4*)(NB + (size_t)r*256 + c) = *(uint4*)o;
}

// ---------------- f16 MFMA GEMM: global_load_lds, BK=64 (2 kb per barrier-pair) ----------------
// C = bn(relu(A @ W[seg] + bias[seg])); A cols [0,KSPLIT) from A0, rest from A1.
// 128x128 tile, 4 waves 2x2, wave 64x64. Per barrier-pair: stage 32 KB (2 kb of A+B),
// then 32 MFMA/wave. Halves barrier/drain count vs BK=32.
template<int K, int KSPLIT, int LDA, int N, int NY, bool SEG>
__global__ __launch_bounds__(256)
void gemm_mfma(const f16_t* __restrict__ A0, const f16_t* __restrict__ A1,
               const f16_t* __restrict__ Wp,
               const float* __restrict__ bias,
               const float* __restrict__ bng, const float* __restrict__ bnb,
               const float* __restrict__ bnm, const float* __restrict__ bnv,
               f16_t* __restrict__ C)
{
    constexpr int NKB = K / 32;               // even: 6 / 16 / 8
    constexpr int NNT = N / 16;
    __shared__ char smem[32768];              // staging [u][A 8KB | B 8KB] x2  U  eps 17408 B
    f16_t* sm = (f16_t*)smem;                 // A(u) at u*4096; B(u) at 8192 + u*4096
    f16_t* eps = (f16_t*)smem;                // epilogue overlay

    const int t = threadIdx.x;
    const int lane = t & 63, wave = t >> 6;
    const int wm = wave >> 1, wn = wave & 1;
    const int quad = lane >> 4, l16 = lane & 15;
    const int id = blockIdx.x;
    const int xcd = id & 7;
    const int jj = id >> 3;
    const int xi = jj / NY;
    const int y  = jj - xi * NY;
    const int r0 = (xi * 8 + xcd) * 128;
    const int n0 = y * 128;
    const int seg = SEG ? seg_of(r0) : 0;
    const int nbase = n0 >> 4;

    f32x4 acc[4][4];
#pragma unroll
    for (int mi = 0; mi < 4; ++mi)
#pragma unroll
        for (int ni = 0; ni < 4; ++ni) acc[mi][ni] = (f32x4){0.f,0.f,0.f,0.f};

    size_t aoff[2];
#pragma unroll
    for (int i = 0; i < 2; ++i)
        aoff[i] = (size_t)(r0 + (wave*2 + i)*16 + l16) * LDA + quad*8;
    size_t bbase[2];
#pragma unroll
    for (int i = 0; i < 2; ++i)
        bbase[i] = ((size_t)(seg*NNT + nbase + wave*2 + i) * NKB) * 512 + lane*8;

#pragma unroll
    for (int kbp = 0; kbp < NKB/2; ++kbp) {
#pragma unroll
        for (int u = 0; u < 2; ++u) {
            const int kb = kbp*2 + u;
            const int kg = kb * 32;
            const f16_t* Ab = (kg < KSPLIT) ? (A0 + kg) : (A1 + (kg - KSPLIT));
#pragma unroll
            for (int i = 0; i < 2; ++i) {
                glds16(Ab + aoff[i], sm + u*4096 + (wave*2 + i)*512);
                glds16(Wp + bbase[i] + (size_t)kb*512, sm + 8192 + u*4096 + (wave*2 + i)*512);
            }
        }
        __syncthreads();
#pragma unroll
        for (int u = 0; u < 2; ++u) {
            half8 a[4], b[4];
#pragma unroll
            for (int mi = 0; mi < 4; ++mi)
                a[mi] = *(const half8*)(sm + u*4096 + (wm*4 + mi)*512 + lane*8);
#pragma unroll
            for (int ni = 0; ni < 4; ++ni)
                b[ni] = *(const half8*)(sm + 8192 + u*4096 + (wn*4 + ni)*512 + lane*8);
#pragma unroll
            for (int mi = 0; mi < 4; ++mi)
#pragma unroll
                for (int ni = 0; ni < 4; ++ni)
                    acc[mi][ni] = __builtin_amdgcn_mfma_f32_16x16x32_f16(a[mi], b[ni], acc[mi][ni], 0, 0, 0);
        }
        __syncthreads();
    }

    // epilogue, two 64-row passes through the LDS overlay
#pragma unroll
    for (int p = 0; p < 2; ++p) {
        if (wm == p) {
#pragma unroll
            for (int ni = 0; ni < 4; ++ni) {
                const int lcol = (wn*4 + ni)*16 + l16;
                const int col = n0 + lcol;
                const float scale = bng[col] * rsqrtf(bnv[col] + 1e-3f);
                const float shift = bnb[col] - bnm[col] * scale;
                const float bv = bias[(SEG ? seg*N : 0) + col];
#pragma unroll
                for (int mi = 0; mi < 4; ++mi) {
                    const int lrowb = mi*16 + quad*4;
#pragma unroll
                    for (int r = 0; r < 4; ++r) {
                        float v = acc[mi][ni][r] + bv;
                        v = fmaxf(v, 0.f);
                        v = fmaf(v, scale, shift);
                        eps[(lrowb + r)*136 + lcol] = (f16_t)v;
                    }
                }
            }
        }
        __syncthreads();
#pragma unroll
        for (int it = 0; it < 4; ++it) {
            int row = it*16 + (t >> 4);
            int ch  = t & 15;
            uint4 v = *(const uint4*)&eps[row*136 + ch*8];
            *(uint4*)(C + (size_t)(r0 + p*64 + row)*N + n0 + ch*8) = v;
        }
        __syncthreads();
    }
}

// ---------------- segment scatter (each segment has exactly 32 atoms) ----------------
__global__ void scatter_k(const int* __restrict__ mem, int* __restrict__ counts, int* __restrict__ slots) {
    int i = blockIdx.x * 256 + threadIdx.x;   // 65536 exact
    int s = mem[i];
    int p = atomicAdd(&counts[s], 1);
    if (p < 32) slots[s*32 + p] = i;
}

// ---------------- segment sum/max over H3[65536x512] -> fp = tanh([ssum|smax]) ----------------
// one wave per segment; lane l owns cols [l*8, l*8+8); 32 coalesced 1-KB row reads
__global__ __launch_bounds__(64)
void reduce_k(const f16_t* __restrict__ H3, const int* __restrict__ slots,
              float* __restrict__ fp, f16_t* __restrict__ fph) {
    int s = blockIdx.x, l = threadIdx.x;
    int c = l * 8;
    const int* sl = slots + s*32;
    float sm[8], mx[8];
#pragma unroll
    for (int e = 0; e < 8; ++e) { sm[e] = 0.f; mx[e] = -INFINITY; }
#pragma unroll
    for (int i = 0; i < 32; ++i) {
        int a = sl[i];
        uint4 raw = *(const uint4*)(H3 + (size_t)a*512 + c);
        const f16_t* u = (const f16_t*)&raw;
#pragma unroll
        for (int e = 0; e < 8; ++e) {
            float f = (float)u[e];
            sm[e] += f;
            mx[e] = fmaxf(mx[e], f);
        }
    }
    float o1[8], o2[8];
    f16_t h1[8], h2[8];
#pragma unroll
    for (int e = 0; e < 8; ++e) {
        o1[e] = tanhf(sm[e]); o2[e] = tanhf(mx[e]);
        h1[e] = (f16_t)o1[e]; h2[e] = (f16_t)o2[e];
    }
    float* fr = fp + (size_t)s*1024;
    *(float4*)(fr + c)       = *(float4*)&o1[0];
    *(float4*)(fr + c + 4)   = *(float4*)&o1[4];
    *(float4*)(fr + 512 + c)     = *(float4*)&o2[0];
    *(float4*)(fr + 512 + c + 4) = *(float4*)&o2[4];
    f16_t* fh = fph + (size_t)s*1024;
    *(uint4*)(fh + c)       = *(uint4*)h1;
    *(uint4*)(fh + 512 + c) = *(uint4*)h2;
}

// ---------------- readout GEMM: logits = fph @ out_w + out_b; probs = pair-softmax ----------------
__global__ __launch_bounds__(256)
void final_mfma(const f16_t* __restrict__ fph, const f16_t* __restrict__ Wop,
                const float* __restrict__ out_b,
                float* __restrict__ probs, float* __restrict__ logits) {
    const int t = threadIdx.x;
    const int lane = t & 63, wave = t >> 6;
    const int quad = lane >> 4, l16 = lane & 15;
    const int r0 = blockIdx.x * 256 + wave * 64;

    f32x4 acc[4][2];
#pragma unroll
    for (int mi = 0; mi < 4; ++mi)
#pragma unroll
        for (int ni = 0; ni < 2; ++ni) acc[mi][ni] = (f32x4){0.f,0.f,0.f,0.f};

    size_t rowoff[4];
#pragma unroll
    for (int mi = 0; mi < 4; ++mi)
        rowoff[mi] = (size_t)(r0 + mi*16 + l16) * 1024 + quad*8;
    size_t boff[2];
#pragma unroll
    for (int ni = 0; ni < 2; ++ni)
        boff[ni] = (size_t)ni * 32 * 512 + lane*8;

    auto loadA = [&](half8* a, int kb) {
#pragma unroll
        for (int mi = 0; mi < 4; ++mi) a[mi] = *(const half8*)(fph + rowoff[mi] + kb*32);
    };
    auto loadB = [&](half8* b, int kb) {
#pragma unroll
        for (int ni = 0; ni < 2; ++ni) b[ni] = *(const half8*)(Wop + boff[ni] + (size_t)kb*512);
    };
    auto domfma = [&](half8* a, half8* b) {
#pragma unroll
        for (int mi = 0; mi < 4; ++mi)
#pragma unroll
            for (int ni = 0; ni < 2; ++ni)
                acc[mi][ni] = __builtin_amdgcn_mfma_f32_16x16x32_f16(a[mi], b[ni], acc[mi][ni], 0, 0, 0);
    };

    half8 a0[4], b0[2], a1[4], b1[2];
    loadA(a0, 0); loadB(b0, 0);
#pragma unroll
    for (int kb = 0; kb < 32; kb += 2) {
        loadA(a1, kb + 1); loadB(b1, kb + 1);
        domfma(a0, b0);
        if (kb + 2 < 32) { loadA(a0, kb + 2); loadB(b0, kb + 2); }
        domfma(a1, b1);
    }

#pragma unroll
    for (int ni = 0; ni < 2; ++ni) {
        const int c = ni*16 + l16;
        const bool ok = (c < 24);
        const float bv = ok ? out_b[c] : 0.f;
#pragma unroll
        for (int mi = 0; mi < 4; ++mi) {
#pragma unroll
            for (int r = 0; r < 4; ++r) {
                float lg = acc[mi][ni][r] + bv;
                float lp = __shfl_xor(lg, 1);
                float m = fmaxf(lg, lp);
                float e  = expf(lg - m);
                float ep = expf(lp - m);
                float pr = e / (e + ep);
                if (ok) {
                    int row = r0 + mi*16 + quad*4 + r;
                    logits[(size_t)row*24 + c] = lg;
                    probs[(size_t)row*24 + c]  = pr;
                }
            }
        }
    }
}

extern "C" void kernel_launch(void* const* d_in, const int* in_sizes, int n_in,
                              void* d_out, int out_size, void* d_ws, size_t ws_size,
                              hipStream_t stream) {
    const float* atom       = (const float*)d_in[0];
    const int*   membership = (const int*)  d_in[2];
    Adj adj;
    for (int d = 0; d < 10; ++d) adj.p[d] = (const int*)d_in[4+d];
    const float* gc1_w0     = (const float*)d_in[14];
    const float* gc1_wself  = (const float*)d_in[15];
    const float* gc1_wneigh = (const float*)d_in[16];
    const float* gc1_b      = (const float*)d_in[17];
    const float* gc2_w0     = (const float*)d_in[18];
    const float* gc2_wself  = (const float*)d_in[19];
    const float* gc2_wneigh = (const float*)d_in[20];
    const float* gc2_b      = (const float*)d_in[21];
    const float* bn1g = (const float*)d_in[22]; const float* bn1b = (const float*)d_in[23];
    const float* bn1m = (const float*)d_in[24]; const float* bn1v = (const float*)d_in[25];
    const float* bn2g = (const float*)d_in[26]; const float* bn2b = (const float*)d_in[27];
    const float* bn2m = (const float*)d_in[28]; const float* bn2v = (const float*)d_in[29];
    const float* bn3g = (const float*)d_in[30]; const float* bn3b = (const float*)d_in[31];
    const float* bn3m = (const float*)d_in[32]; const float* bn3v = (const float*)d_in[33];
    const float* dense_w = (const float*)d_in[34];
    const float* dense_b = (const float*)d_in[35];
    const float* out_w   = (const float*)d_in[36];
    const float* out_b   = (const float*)d_in[37];

    // workspace layout in f16 elements (2 B each)
    f16_t* wsb = (f16_t*)d_ws;
    f16_t* xq   = wsb;                       //  6,291,456
    f16_t* NBX  = wsb + 6291456;             //  6,291,456
    f16_t* H1b  = wsb + 12582912;            // 16,777,216
    f16_t* P1b  = wsb + 29360128;            // 16,777,216
    f16_t* NB2b = wsb + 46137344;            // 16,777,216
    f16_t* H2b  = H1b;
    f16_t* P2b  = NB2b;
    f16_t* H3b  = H1b;                       // 33,554,432 spans H1+P1
    f16_t* W1p  = wsb + 62914560;            //    540,672
    f16_t* W2p  = wsb + 63455232;            //  1,441,792
    f16_t* Wdp  = wsb + 64897024;            //    131,072
    f16_t* fph  = wsb + 65028096;            //  2,097,152 (2048x1024 f16)
    f16_t* Wop  = wsb + 67125248;            //     32,768
    int*  counts = (int*)(wsb + 67158016);   // 2048 ints
    int*  slots  = counts + 2048;            // 65536 ints

    float* outp   = (float*)d_out;
    float* probs  = outp;            // 2048*24
    float* logits = outp + 49152;    // 2048*24
    float* fp     = outp + 98304;    // 2048*1024

    // weight packing
    pack_w1<<<2112, 256, 0, stream>>>(gc1_w0, gc1_wself, gc1_wneigh, W1p);
    pack_w2<<<5632, 256, 0, stream>>>(gc2_w0, gc2_wself, gc2_wneigh, W2p);
    pack_wd<<<512,  256, 0, stream>>>(dense_w, Wdp);
    pack_wo<<<128,  256, 0, stream>>>(out_w, Wop);

    // gc1: xq (self, k<96) + NBX (neigh, k>=96)
    cvt_pad<<<(NATOMS*96)/256, 256, 0, stream>>>(atom, xq);
    nbsum_x<<<(NATOMS*16)/256, 256, 0, stream>>>(xq, NBX, adj);
    gemm_mfma<192,96,96,256,2,true><<<1024, 256, 0, stream>>>(
        xq, NBX, W1p, gc1_b, bn1g, bn1b, bn1m, bn1v, H1b);
    pool_k<<<(NATOMS*32)/256, 256, 0, stream>>>(H1b, P1b, adj);

    // gc2
    nbsum_k<<<(NATOMS*32)/256, 256, 0, stream>>>(P1b, NB2b, adj);
    gemm_mfma<512,256,256,256,2,true><<<1024, 256, 0, stream>>>(
        P1b, NB2b, W2p, gc2_b, bn2g, bn2b, bn2m, bn2v, H2b);
    pool_k<<<(NATOMS*32)/256, 256, 0, stream>>>(H2b, P2b, adj);

    // dense
    gemm_mfma<256,256,256,512,4,false><<<2048, 256, 0, stream>>>(
        P2b, P2b, Wdp, dense_b, bn3g, bn3b, bn3m, bn3v, H3b);

    // segment reduce + tanh -> fp (fp32 to out) + fph (f16 to ws)
    hipMemsetAsync((void*)counts, 0, 2048*sizeof(int), stream);
    scatter_k<<<NATOMS/256, 256, 0, stream>>>(membership, counts, slots);
    reduce_k<<<2048, 64, 0, stream>>>(H3b, slots, fp, fph);

    // readout
    final_mfma<<<8, 256, 0, stream>>>(fph, Wop, out_b, probs, logits);
}